// Round 11
// baseline (338244.922 us; speedup 1.0000x reference)
//
#include <hip/hip_runtime.h>

__device__ __forceinline__ float sigm(float x){ return 1.0f/(1.0f+__expf(-x)); }
__device__ __forceinline__ float tanh_(float x){ float e=__expf(-2.0f*x); return (1.0f-e)/(1.0f+e); }

// ---- transliteration kernels: one per reference op, f32, global memory ----

__global__ void shift_k(const float* __restrict__ target, float* __restrict__ tgt){
  int i = blockIdx.x*256 + threadIdx.x;
  if (i >= 64*80*400) return;
  int t = i % 400;
  tgt[i] = (t==0) ? 0.f : target[i-1];
}

__global__ void pre1_k(const float* __restrict__ tgt, const float* __restrict__ W1,
                       const float* __restrict__ b1, float* __restrict__ x1){
  int i = blockIdx.x*256 + threadIdx.x;
  if (i >= 64*256*400) return;
  int t = i % 400; int o = (i/400) % 256; int b = i/(400*256);
  float s = b1[o];
  for (int c=0;c<80;c++) s += tgt[((size_t)b*80+c)*400+t] * W1[o*80+c];
  x1[i] = fmaxf(s, 0.f);
}

__global__ void pre2_k(const float* __restrict__ x1, const float* __restrict__ W2,
                       const float* __restrict__ b2, float* __restrict__ x2){
  int i = blockIdx.x*256 + threadIdx.x;
  if (i >= 64*256*400) return;
  int t = i % 400; int o = (i/400) % 256; int b = i/(400*256);
  float s = b2[o];
  for (int c=0;c<256;c++) s += x1[((size_t)b*256+c)*400+t] * W2[o*256+c];
  x2[i] = fmaxf(s, 0.f);
}

__global__ void keyp_k(const float* __restrict__ xin, const float* __restrict__ Wk,
                       float* __restrict__ kp){
  int i = blockIdx.x*256 + threadIdx.x;
  if (i >= 64*256*128) return;
  int m = i % 128; int t = (i/128) % 256; int b = i/(128*256);
  float s = 0.f;
  for (int f=0;f<512;f++) s += xin[((size_t)b*256+t)*512+f] * Wk[m*512+f];
  kp[i] = s;
}

__global__ void prep_k(const float* bih1,const float* bhh1,const float* bih2,const float* bhh2,
                       float* bsum1,float* bsum2){
  int i0 = blockIdx.x*blockDim.x + threadIdx.x;
  int n = gridDim.x*blockDim.x;
  for(int k=i0;k<4096;k+=n){ bsum1[k]=bih1[k]+bhh1[k]; bsum2[k]=bih2[k]+bhh2[k]; }
}

// detect mask encoding: int32 elements (words all in {0,1}) vs bool bytes.
__global__ void maskdet_k(const unsigned* __restrict__ m32, int* __restrict__ flag){
  __shared__ int ok;
  if (threadIdx.x==0) ok = 1;
  __syncthreads();
  for (int i=threadIdx.x; i<4096; i+=256){
    if (m32[i] > 1u) ok = 0;   // benign race: all writers store 0
  }
  __syncthreads();
  if (threadIdx.x==0) *flag = ok;
}

__global__ void lstm1_k(const float* __restrict__ x2, int tau, const float* __restrict__ ctx,
                        const float* __restrict__ h1in, const float* __restrict__ Wih1,
                        const float* __restrict__ Whh1, const float* __restrict__ bs1,
                        float* __restrict__ c1, float* __restrict__ h1out){
  int i = blockIdx.x*256 + threadIdx.x;
  if (i >= 64*1024) return;
  int u = i % 1024; int b = i/1024;
  float g[4];
  for (int gg=0; gg<4; gg++){
    const float* wi = Wih1 + (size_t)(gg*1024+u)*768;
    const float* wh = Whh1 + (size_t)(gg*1024+u)*1024;
    float s = bs1[gg*1024+u];
    for (int c=0;c<256;c++) s += x2[((size_t)b*256+c)*400+tau] * wi[c];
    for (int f=0;f<512;f++) s += ctx[b*512+f] * wi[256+f];
    for (int h=0;h<1024;h++) s += h1in[b*1024+h] * wh[h];
    g[gg]=s;
  }
  float cn = sigm(g[1])*c1[i] + sigm(g[0])*tanh_(g[2]);
  c1[i]=cn;
  h1out[i]=sigm(g[3])*tanh_(cn);
}

__global__ void conv_k(const float* __restrict__ aw, const float* __restrict__ awc,
                       const float* __restrict__ lconv, float* __restrict__ loc){
  int i = blockIdx.x*256 + threadIdx.x;
  if (i >= 64*32*256) return;
  int t = i % 256; int f = (i/256)%32; int b = i/(256*32);
  float s=0.f;
  for (int c=0;c<2;c++){
    const float* w = (c==0)? aw : awc;
    for (int k=0;k<31;k++){
      int tt = t+k-15;
      if (tt>=0 && tt<256) s += w[b*256+tt]*lconv[(f*2+c)*31+k];
    }
  }
  loc[i]=s;
}

__global__ void q_k(const float* __restrict__ h1, const float* __restrict__ Wq,
                    float* __restrict__ q){
  int i = blockIdx.x*256 + threadIdx.x;
  if (i >= 64*128) return;
  int m = i%128; int b = i/128;
  float s=0.f;
  for (int h=0;h<1024;h++) s += h1[b*1024+h]*Wq[m*1024+h];
  q[i]=s;
}

// e[b][t] = mask[b][t] ? sum_m tanh(q + kp + loc.Wloc)*v : -1e9
__global__ void e_k(const float* __restrict__ q, const float* __restrict__ kp,
                    const float* __restrict__ loc, const float* __restrict__ Wloc,
                    const float* __restrict__ v,
                    const unsigned char* __restrict__ mask8,
                    const int* __restrict__ mask32,
                    const int* __restrict__ mflag,
                    float* __restrict__ e){
  int i = blockIdx.x*256 + threadIdx.x;
  if (i >= 64*256) return;
  int t = i%256; int b = i/256;
  float s=0.f;
  for (int m=0;m<128;m++){
    float lf=0.f;
    for (int f=0;f<32;f++) lf += loc[((size_t)b*32+f)*256+t]*Wloc[m*32+f];
    s += tanh_(q[b*128+m] + kp[((size_t)b*256+t)*128+m] + lf)*v[m];
  }
  bool mv = (*mflag) ? (mask32[b*256+t] != 0) : (mask8[b*256+t] != 0);
  e[i] = mv ? s : -1e9f;
}

__global__ void soft_k(const float* __restrict__ e, const float* __restrict__ xin,
                       float* __restrict__ aw, float* __restrict__ awc, float* __restrict__ ctx,
                       float* __restrict__ wout, int tau){
  int b = blockIdx.x; int t = threadIdx.x;
  __shared__ float sw[256];
  __shared__ float red2[8];
  float ev = e[b*256+t];
  float mx = ev;
  #pragma unroll
  for(int off=1;off<64;off<<=1) mx = fmaxf(mx, __shfl_xor(mx,off));
  if ((t&63)==0) red2[t>>6]=mx;
  __syncthreads();
  mx = fmaxf(fmaxf(red2[0],red2[1]),fmaxf(red2[2],red2[3]));
  float pe = __expf(ev-mx);
  float sm=pe;
  #pragma unroll
  for(int off=1;off<64;off<<=1) sm += __shfl_xor(sm,off);
  if ((t&63)==0) red2[4+(t>>6)]=sm;
  __syncthreads();
  sm = red2[4]+red2[5]+red2[6]+red2[7];
  float awt = pe/sm;
  sw[t]=awt;
  aw[b*256+t]=awt;
  awc[b*256+t]+=awt;
  wout[(size_t)b*102400 + (size_t)t*400 + tau] = awt;
  __syncthreads();
  for (int f=t; f<512; f+=256){
    float s=0.f;
    for (int tt=0;tt<256;tt++) s += sw[tt]*xin[((size_t)b*256+tt)*512+f];
    ctx[b*512+f]=s;
  }
}

__global__ void lstm2_k(const float* __restrict__ h1, const float* __restrict__ ctx,
                        const float* __restrict__ h2in, const float* __restrict__ Wih2,
                        const float* __restrict__ Whh2, const float* __restrict__ bs2,
                        float* __restrict__ c2, float* __restrict__ h2out){
  int i = blockIdx.x*256 + threadIdx.x;
  if (i >= 64*1024) return;
  int u = i%1024; int b = i/1024;
  float g[4];
  for (int gg=0;gg<4;gg++){
    const float* wi = Wih2 + (size_t)(gg*1024+u)*1536;
    const float* wh = Whh2 + (size_t)(gg*1024+u)*1024;
    float s = bs2[gg*1024+u];
    for (int h=0;h<1024;h++) s += h1[b*1024+h]*wi[h];
    for (int f=0;f<512;f++) s += ctx[b*512+f]*wi[1024+f];
    for (int h=0;h<1024;h++) s += h2in[b*1024+h]*wh[h];
    g[gg]=s;
  }
  float cn = sigm(g[1])*c2[i] + sigm(g[0])*tanh_(g[2]);
  c2[i]=cn;
  h2out[i]=sigm(g[3])*tanh_(cn);
}

__global__ void out_k(const float* __restrict__ h2, const float* __restrict__ ctx,
                      const float* __restrict__ Wout, const float* __restrict__ bout,
                      float* __restrict__ outp, int tau){
  int i = blockIdx.x*256 + threadIdx.x;
  if (i >= 64*80) return;
  int nm = i%80; int b = i/80;
  float s = bout[nm];
  for (int h=0;h<1024;h++) s += h2[b*1024+h]*Wout[nm*1536+h];
  for (int f=0;f<512;f++) s += ctx[b*512+f]*Wout[nm*1536+1024+f];
  outp[(size_t)b*32000 + nm*400 + tau] = s;
}

extern "C" void kernel_launch(void* const* d_in, const int* in_sizes, int n_in,
                              void* d_out, int out_size, void* d_ws, size_t ws_size,
                              hipStream_t stream){
  (void)in_sizes; (void)n_in; (void)out_size; (void)ws_size;
  const float* xin   = (const float*)d_in[0];
  const unsigned char* mask8 = (const unsigned char*)d_in[1];
  const int* mask32  = (const int*)d_in[1];
  const float* target= (const float*)d_in[2];
  const float* Wpre1 = (const float*)d_in[3];
  const float* bpre1 = (const float*)d_in[4];
  const float* Wpre2 = (const float*)d_in[5];
  const float* bpre2 = (const float*)d_in[6];
  const float* Wq    = (const float*)d_in[7];
  const float* Wk    = (const float*)d_in[8];
  const float* loc_conv = (const float*)d_in[9];
  const float* Wloc  = (const float*)d_in[10];
  const float* v_att = (const float*)d_in[11];
  const float* Wih1  = (const float*)d_in[12];
  const float* Whh1  = (const float*)d_in[13];
  const float* bih1  = (const float*)d_in[14];
  const float* bhh1  = (const float*)d_in[15];
  const float* Wih2  = (const float*)d_in[16];
  const float* Whh2  = (const float*)d_in[17];
  const float* bih2  = (const float*)d_in[18];
  const float* bhh2  = (const float*)d_in[19];
  const float* Wout  = (const float*)d_in[20];
  const float* boutp = (const float*)d_in[21];

  char* w = (char*)d_ws;
  auto carve=[&](size_t bytes)->void*{ void* r=(void*)w; w += (bytes+255)&~(size_t)255; return r; };
  // state (zeroed every launch) — contiguous, first
  float* h1buf = (float*)carve((size_t)2*64*1024*4);
  float* h2buf = (float*)carve((size_t)2*64*1024*4);
  float* c1   = (float*)carve((size_t)64*1024*4);
  float* c2   = (float*)carve((size_t)64*1024*4);
  float* aw   = (float*)carve((size_t)64*256*4);
  float* awc  = (float*)carve((size_t)64*256*4);
  float* ctx  = (float*)carve((size_t)64*512*4);
  size_t state_bytes = (size_t)(w - (char*)d_ws);
  float* tgt  = (float*)carve((size_t)64*80*400*4);
  float* x1   = (float*)carve((size_t)64*256*400*4);
  float* x2   = (float*)carve((size_t)64*256*400*4);
  float* kp   = (float*)carve((size_t)64*256*128*4);
  float* loc  = (float*)carve((size_t)64*32*256*4);
  float* q    = (float*)carve((size_t)64*128*4);
  float* e    = (float*)carve((size_t)64*256*4);
  float* bsum1= (float*)carve((size_t)4096*4);
  float* bsum2= (float*)carve((size_t)4096*4);
  int*   mflag= (int*)carve(256);

  float* outp = (float*)d_out;
  float* wout = (float*)d_out + (size_t)64*80*400;

  hipMemsetAsync(d_ws, 0, state_bytes, stream);
  maskdet_k<<<1, 256, 0, stream>>>((const unsigned*)d_in[1], mflag);
  shift_k<<<8000, 256, 0, stream>>>(target, tgt);
  pre1_k<<<25600, 256, 0, stream>>>(tgt, Wpre1, bpre1, x1);
  pre2_k<<<25600, 256, 0, stream>>>(x1, Wpre2, bpre2, x2);
  keyp_k<<<8192, 256, 0, stream>>>(xin, Wk, kp);
  prep_k<<<16, 256, 0, stream>>>(bih1, bhh1, bih2, bhh2, bsum1, bsum2);

  for (int tau=0; tau<400; ++tau){
    const float* h1_old = h1buf + (size_t)(tau&1)*65536;
    float*       h1_new = h1buf + (size_t)((tau+1)&1)*65536;
    const float* h2_old = h2buf + (size_t)(tau&1)*65536;
    float*       h2_new = h2buf + (size_t)((tau+1)&1)*65536;
    lstm1_k<<<256, 256, 0, stream>>>(x2, tau, ctx, h1_old, Wih1, Whh1, bsum1, c1, h1_new);
    conv_k<<<2048, 256, 0, stream>>>(aw, awc, loc_conv, loc);
    q_k<<<32, 256, 0, stream>>>(h1_new, Wq, q);
    e_k<<<64, 256, 0, stream>>>(q, kp, loc, Wloc, v_att, mask8, mask32, mflag, e);
    soft_k<<<64, 256, 0, stream>>>(e, xin, aw, awc, ctx, wout, tau);
    lstm2_k<<<256, 256, 0, stream>>>(h1_new, ctx, h2_old, Wih2, Whh2, bsum2, c2, h2_new);
    out_k<<<20, 256, 0, stream>>>(h2_new, ctx, Wout, boutp, outp, tau);
  }
}

// Round 12
// 85688.599 us; speedup vs baseline: 3.9474x; 3.9474x over previous
//
#include <hip/hip_runtime.h>

#define NB 256
#define NT 256

typedef __attribute__((ext_vector_type(8))) short short8;
typedef __attribute__((ext_vector_type(4))) float f32x4;

__device__ __forceinline__ float b2f(unsigned short s){ return __uint_as_float(((unsigned)s)<<16); }
__device__ __forceinline__ unsigned short f2b(float f){
  unsigned u = __float_as_uint(f);
  return (unsigned short)((u + 0x7FFFu + ((u>>16)&1u))>>16);
}
__device__ __forceinline__ float sigm(float x){ return 1.0f/(1.0f+__expf(-x)); }
__device__ __forceinline__ float tanh_(float x){ float e=__expf(-2.0f*x); return (1.0f-e)/(1.0f+e); }
__device__ __forceinline__ f32x4 mfma16(short8 a, short8 b, f32x4 c){
  return __builtin_amdgcn_mfma_f32_16x16x32_bf16(a,b,c,0,0,0);
}

// grid barrier: monotonic target, device-scope. Validated R3-R5 (bit-identical
// trajectories vs stream-serialized kernels).
__device__ __forceinline__ void gbar(unsigned* bar, unsigned& target){
  __syncthreads();
  if (threadIdx.x==0){
    target += NB;
    __threadfence();
    atomicAdd(bar, 1u);
    while (__hip_atomic_load(bar, __ATOMIC_ACQUIRE, __HIP_MEMORY_SCOPE_AGENT) < target){
      __builtin_amdgcn_s_sleep(1);
    }
    __threadfence();
  }
  __syncthreads();
}

// ---------------- precompute kernels ----------------

__global__ void maskdet_k(const unsigned* __restrict__ m32, int* __restrict__ flag){
  __shared__ int ok;
  if (threadIdx.x==0) ok = 1;
  __syncthreads();
  for (int i=threadIdx.x; i<4096; i+=256){
    if (m32[i] > 1u) ok = 0;
  }
  __syncthreads();
  if (threadIdx.x==0) *flag = ok;
}

__global__ void prenet_k(const float* __restrict__ target, const float* __restrict__ W1, const float* __restrict__ b1,
                         const float* __restrict__ W2, const float* __restrict__ b2,
                         unsigned short* __restrict__ xbh, unsigned short* __restrict__ xbl){
  int t = blockIdx.x;
  int tid = threadIdx.x;
  __shared__ float stgt[64][80];
  __shared__ float smid[64][256];
  for(int i=tid;i<64*80;i+=256){
    int b=i/80, c=i%80;
    stgt[b][c] = (t==0)?0.f : target[((size_t)b*80+c)*400 + (t-1)];
  }
  __syncthreads();
  {
    float w1r[80];
    #pragma unroll
    for(int c=0;c<80;c++) w1r[c] = W1[tid*80+c];
    float bb1 = b1[tid];
    for(int b0=0;b0<64;b0+=16){
      float acc[16];
      #pragma unroll
      for(int i=0;i<16;i++) acc[i]=0.f;
      for(int c=0;c<80;c++){
        float wv=w1r[c];
        #pragma unroll
        for(int i=0;i<16;i++) acc[i] += wv*stgt[b0+i][c];
      }
      #pragma unroll
      for(int i=0;i<16;i++) smid[b0+i][tid] = fmaxf(acc[i]+bb1, 0.f);
    }
  }
  __syncthreads();
  {
    float bb2 = b2[tid];
    for(int b0=0;b0<64;b0+=16){
      float acc[16];
      #pragma unroll
      for(int i=0;i<16;i++) acc[i]=0.f;
      for(int c=0;c<256;c++){
        float wv=W2[tid*256+c];
        #pragma unroll
        for(int i=0;i<16;i++) acc[i] += wv*smid[b0+i][c];
      }
      #pragma unroll
      for(int i=0;i<16;i++){
        float v = fmaxf(acc[i]+bb2,0.f);
        size_t idx = ((size_t)t*64 + b0+i)*256 + tid;
        unsigned short h = f2b(v);
        xbh[idx] = h;
        xbl[idx] = f2b(v - b2f(h));
      }
    }
  }
}

__global__ void keyproj_k(const float* __restrict__ xin, const float* __restrict__ Wk, float* __restrict__ keyp){
  int b = blockIdx.x>>4; int t0=(blockIdx.x&15)*16; int m=threadIdx.x; // 128 threads
  __shared__ float sx[16][512];
  for(int i=m;i<16*512;i+=128){ int tt=i>>9, f=i&511; sx[tt][f]=xin[((size_t)b*256+t0+tt)*512+f]; }
  __syncthreads();
  float s[16];
  #pragma unroll
  for(int i=0;i<16;i++) s[i]=0.f;
  for(int f=0;f<512;f++){
    float wv = Wk[m*512+f];
    #pragma unroll
    for(int i=0;i<16;i++) s[i]+=sx[i][f]*wv;
  }
  #pragma unroll
  for(int i=0;i<16;i++) keyp[((size_t)b*256+t0+i)*128+m]=s[i];
}

__global__ void prep_k(const float* bih1,const float* bhh1,const float* bih2,const float* bhh2,
                       float* bsum1,float* bsum2){
  int i0 = blockIdx.x*blockDim.x + threadIdx.x;
  int n = gridDim.x*blockDim.x;
  for(int k=i0;k<4096;k+=n){ bsum1[k]=bih1[k]+bhh1[k]; bsum2[k]=bih2[k]+bhh2[k]; }
}

__global__ void perm_k(const float* __restrict__ Wih1, const float* __restrict__ Whh1,
                       const float* __restrict__ Wih2, const float* __restrict__ Whh2,
                       unsigned short* __restrict__ Wp1h, unsigned short* __restrict__ Wp1l,
                       unsigned short* __restrict__ Wp2h, unsigned short* __restrict__ Wp2l){
  size_t i0 = (size_t)blockIdx.x*blockDim.x + threadIdx.x;
  size_t n  = (size_t)gridDim.x*blockDim.x;
  const size_t N1 = (size_t)256*56*512;
  for(size_t idx=i0; idx<N1; idx+=n){
    int beta = (int)(idx/28672);
    int r = (int)(idx%28672);
    int kt = r/512;
    int l  = (r>>3)&63;
    int i8 = r&7;
    int c = l&15, cci = l>>4;
    int k = kt*32 + cci*8 + i8;
    int rowp = (c>>2)*1024 + beta*4 + (c&3);
    float v = (k<768)? Wih1[(size_t)rowp*768 + k] : Whh1[(size_t)rowp*1024 + (k-768)];
    unsigned short h = f2b(v);
    Wp1h[idx] = h;
    Wp1l[idx] = f2b(v - b2f(h));
  }
  const size_t N2 = (size_t)256*80*512;
  for(size_t idx=i0; idx<N2; idx+=n){
    int beta = (int)(idx/40960);
    int r = (int)(idx%40960);
    int kt = r/512;
    int l  = (r>>3)&63;
    int i8 = r&7;
    int c = l&15, cci = l>>4;
    int k = kt*32 + cci*8 + i8;
    int rowp = (c>>2)*1024 + beta*4 + (c&3);
    float v = (k<1536)? Wih2[(size_t)rowp*1536 + k] : Whh2[(size_t)rowp*1024 + (k-1536)];
    unsigned short h = f2b(v);
    Wp2h[idx] = h;
    Wp2l[idx] = f2b(v - b2f(h));
  }
}

// ---------------- the scan (persistent, custom grid barrier) ----------------

struct SArgs {
  const float* xin; const float* loc_conv; const float* Wloc; const float* v_att; const float* bout;
  const float* Wq; const float* Wout;
  const float* keyp;
  const unsigned short* xbh; const unsigned short* xbl;
  const unsigned short* Wp1h; const unsigned short* Wp1l;
  const unsigned short* Wp2h; const unsigned short* Wp2l;
  const float* bsum1; const float* bsum2;
  const unsigned char* mask8; const int* mask32; const int* mflag;
  unsigned short* h1h; unsigned short* h1l; float* h1f;
  unsigned short* h2h; unsigned short* h2l; float* h2f;
  unsigned short* ctxh; unsigned short* ctxl; float* ctxf;
  float* c1; float* c2;
  float* aw; float* awc; float* eP; float* locT;
  unsigned* bar;
  float* outp; float* wout;
};

__global__ void __launch_bounds__(NT) scan_kernel(SArgs a){
  const int beta = blockIdx.x;
  const int tid = threadIdx.x;
  const int wav = tid>>6;
  const int lan = tid&63;

  __shared__ float gsc[64][17];
  __shared__ float sA[2560];
  __shared__ float sq[32];
  __shared__ float sv[32];
  __shared__ float red[8];

  const int row = wav*16 + (lan&15);
  const int cc  = lan>>4;
  const int b4  = beta>>2;
  const int q4  = beta&3;
  unsigned bt = 0;

  // mask value for this thread's (b4, t=tid) attention position — constant over tau
  const bool mv = (a.mflag[0] ? (a.mask32[b4*256+tid] != 0) : (a.mask8[b4*256+tid] != 0));

  for (int tau=0; tau<=400; ++tau){
    const int p = tau&1;
    // ================= Phase A =================
    if (tau<400){
      // LSTM1 gates, step tau: X = [xb_tau | ctx_{tau-1} | h1_{tau-1}], K=1792
      // split-bf16 3-product GEMM: hi*hi + hi*lo + lo*hi
      f32x4 A0={0.f,0.f,0.f,0.f}, A1={0.f,0.f,0.f,0.f}, A2={0.f,0.f,0.f,0.f};
      const unsigned short* wh = a.Wp1h + (size_t)beta*28672 + lan*8;
      const unsigned short* wl = a.Wp1l + (size_t)beta*28672 + lan*8;
      {
        const unsigned short* xh = a.xbh + ((size_t)tau*64 + row)*256 + cc*8;
        const unsigned short* xl = a.xbl + ((size_t)tau*64 + row)*256 + cc*8;
        #pragma unroll
        for(int kt=0;kt<8;kt++){
          short8 ah=*(const short8*)(xh+kt*32), al=*(const short8*)(xl+kt*32);
          short8 bh=*(const short8*)(wh+kt*512), bl=*(const short8*)(wl+kt*512);
          A0=mfma16(ah,bh,A0); A1=mfma16(ah,bl,A1); A2=mfma16(al,bh,A2);
        }
      }
      {
        const unsigned short* xh = a.ctxh + row*512 + cc*8;
        const unsigned short* xl = a.ctxl + row*512 + cc*8;
        #pragma unroll 4
        for(int kt=8;kt<24;kt++){
          short8 ah=*(const short8*)(xh+(kt-8)*32), al=*(const short8*)(xl+(kt-8)*32);
          short8 bh=*(const short8*)(wh+kt*512), bl=*(const short8*)(wl+kt*512);
          A0=mfma16(ah,bh,A0); A1=mfma16(ah,bl,A1); A2=mfma16(al,bh,A2);
        }
      }
      {
        const unsigned short* xh = a.h1h + (size_t)(p^1)*65536 + row*1024 + cc*8;
        const unsigned short* xl = a.h1l + (size_t)(p^1)*65536 + row*1024 + cc*8;
        #pragma unroll 4
        for(int kt=24;kt<56;kt++){
          short8 ah=*(const short8*)(xh+(kt-24)*32), al=*(const short8*)(xl+(kt-24)*32);
          short8 bh=*(const short8*)(wh+kt*512), bl=*(const short8*)(wl+kt*512);
          A0=mfma16(ah,bh,A0); A1=mfma16(ah,bl,A1); A2=mfma16(al,bh,A2);
        }
      }
      #pragma unroll
      for(int r=0;r<4;r++) gsc[wav*16 + cc*4 + r][lan&15] = A0[r]+A1[r]+A2[r];
    }
    __syncthreads();
    if (tau<400){
      int m = tid>>2, j = tid&3, u = beta*4+j;
      float gi = gsc[m][0+j]  + a.bsum1[0*1024+u];
      float gf = gsc[m][4+j]  + a.bsum1[1*1024+u];
      float gg = gsc[m][8+j]  + a.bsum1[2*1024+u];
      float go = gsc[m][12+j] + a.bsum1[3*1024+u];
      float cp = a.c1[m*1024+u];
      float cn = sigm(gf)*cp + sigm(gi)*tanh_(gg);
      a.c1[m*1024+u] = cn;
      float hn = sigm(go)*tanh_(cn);
      a.h1f[m*1024+u] = hn;
      unsigned short hh = f2b(hn);
      a.h1h[(size_t)p*65536 + m*1024 + u] = hh;
      a.h1l[(size_t)p*65536 + m*1024 + u] = f2b(hn - b2f(hh));
    }
    __syncthreads();
    if (tau>0){
      // LSTM2 gates, step tau-1: X = [h1_{tau-1} | ctx_{tau-1} | h2_{tau-2}], K=2560
      f32x4 A0={0.f,0.f,0.f,0.f}, A1={0.f,0.f,0.f,0.f}, A2={0.f,0.f,0.f,0.f};
      const unsigned short* wh = a.Wp2h + (size_t)beta*40960 + lan*8;
      const unsigned short* wl = a.Wp2l + (size_t)beta*40960 + lan*8;
      {
        const unsigned short* xh = a.h1h + (size_t)(p^1)*65536 + row*1024 + cc*8;
        const unsigned short* xl = a.h1l + (size_t)(p^1)*65536 + row*1024 + cc*8;
        #pragma unroll 4
        for(int kt=0;kt<32;kt++){
          short8 ah=*(const short8*)(xh+kt*32), al=*(const short8*)(xl+kt*32);
          short8 bh=*(const short8*)(wh+kt*512), bl=*(const short8*)(wl+kt*512);
          A0=mfma16(ah,bh,A0); A1=mfma16(ah,bl,A1); A2=mfma16(al,bh,A2);
        }
      }
      {
        const unsigned short* xh = a.ctxh + row*512 + cc*8;
        const unsigned short* xl = a.ctxl + row*512 + cc*8;
        #pragma unroll 4
        for(int kt=32;kt<48;kt++){
          short8 ah=*(const short8*)(xh+(kt-32)*32), al=*(const short8*)(xl+(kt-32)*32);
          short8 bh=*(const short8*)(wh+kt*512), bl=*(const short8*)(wl+kt*512);
          A0=mfma16(ah,bh,A0); A1=mfma16(ah,bl,A1); A2=mfma16(al,bh,A2);
        }
      }
      {
        const unsigned short* xh = a.h2h + (size_t)p*65536 + row*1024 + cc*8;
        const unsigned short* xl = a.h2l + (size_t)p*65536 + row*1024 + cc*8;
        #pragma unroll 4
        for(int kt=48;kt<80;kt++){
          short8 ah=*(const short8*)(xh+(kt-48)*32), al=*(const short8*)(xl+(kt-48)*32);
          short8 bh=*(const short8*)(wh+kt*512), bl=*(const short8*)(wl+kt*512);
          A0=mfma16(ah,bh,A0); A1=mfma16(ah,bl,A1); A2=mfma16(al,bh,A2);
        }
      }
      #pragma unroll
      for(int r=0;r<4;r++) gsc[wav*16 + cc*4 + r][lan&15] = A0[r]+A1[r]+A2[r];
    }
    __syncthreads();
    if (tau>0){
      int m = tid>>2, j = tid&3, u = beta*4+j;
      float gi = gsc[m][0+j]  + a.bsum2[0*1024+u];
      float gf = gsc[m][4+j]  + a.bsum2[1*1024+u];
      float gg = gsc[m][8+j]  + a.bsum2[2*1024+u];
      float go = gsc[m][12+j] + a.bsum2[3*1024+u];
      float cp = a.c2[m*1024+u];
      float cn = sigm(gf)*cp + sigm(gi)*tanh_(gg);
      a.c2[m*1024+u] = cn;
      float hn = sigm(go)*tanh_(cn);
      a.h2f[m*1024+u] = hn;
      unsigned short hh = f2b(hn);
      a.h2h[(size_t)(p^1)*65536 + m*1024 + u] = hh;
      a.h2l[(size_t)(p^1)*65536 + m*1024 + u] = f2b(hn - b2f(hh));
    }
    if (tau<400){
      // location features for step tau (uses aw_{tau-1}, awc_{tau-1})
      for(int i=tid;i<256;i+=NT){ sA[i] = a.aw[b4*256+i]; sA[256+i] = a.awc[b4*256+i]; }
      for(int i=tid;i<1984;i+=NT) sA[512+i] = a.loc_conv[i];
      __syncthreads();
      const int t0 = q4*64;
      #pragma unroll
      for(int jj=0;jj<8;jj++){
        int o = tid*8+jj;
        int f = o>>6, tl = o&63, t = t0+tl;
        float s = 0.f;
        #pragma unroll
        for(int c=0;c<2;c++){
          const float* kw = &sA[512 + (f*2+c)*31];
          const float* wv = &sA[c*256];
          for(int k=0;k<31;k++){
            int tt = t + k - 15;
            if (tt>=0 && tt<256) s += wv[tt]*kw[k];
          }
        }
        a.locT[(size_t)b4*8192 + f*256 + t] = s;
      }
    }
    gbar(a.bar, bt);
    // ================= Phase B =================
    if (tau<400){
      for(int i=tid;i<1024;i+=NT) sA[i] = a.h1f[b4*1024 + i];
      __syncthreads();
      {
        int ml = tid>>3, sg = tid&7;
        const float* wq = a.Wq + (size_t)(q4*32+ml)*1024;
        float s=0.f;
        #pragma unroll 8
        for(int i=0;i<128;i++) s += sA[sg + i*8]*wq[sg + i*8];
        s += __shfl_xor(s,1); s += __shfl_xor(s,2); s += __shfl_xor(s,4);
        if (sg==0) sq[ml] = s;
      }
      __syncthreads();
      for(int i=tid;i<1024;i+=NT) sA[i] = a.Wloc[(q4*32 + (i>>5))*32 + (i&31)];
      if (tid<32) sv[tid] = a.v_att[q4*32+tid];
      __syncthreads();
      {
        int t = tid;
        float lc[32];
        const float* lb = a.locT + (size_t)b4*8192 + t;
        #pragma unroll
        for(int f=0;f<32;f++) lc[f] = lb[f*256];
        const float* kb = a.keyp + ((size_t)b4*256 + t)*128 + q4*32;
        float acc=0.f;
        for(int mm=0;mm<32;mm++){
          float lf=0.f;
          #pragma unroll
          for(int f=0;f<32;f++) lf += lc[f]*sA[mm*32+f];
          acc += tanh_(sq[mm] + kb[mm] + lf)*sv[mm];
        }
        a.eP[b4*1024 + t*4 + q4] = acc;
      }
    }
    if (tau>0){
      __syncthreads();
      for(int i=tid;i<1024;i+=NT) sA[i] = a.h2f[b4*1024 + i];
      for(int i=tid;i<512;i+=NT) sA[1024+i] = a.ctxf[b4*512+i];
      __syncthreads();
      if (tid<160){
        int nl = tid>>3, sg = tid&7, nm = q4*20+nl;
        const float* wo = a.Wout + (size_t)nm*1536;
        float s=0.f;
        #pragma unroll 8
        for(int i=0;i<192;i++) s += sA[sg + i*8]*wo[sg + i*8];
        s += __shfl_xor(s,1); s += __shfl_xor(s,2); s += __shfl_xor(s,4);
        if (sg==0) a.outp[(size_t)b4*32000 + nm*400 + (tau-1)] = s + a.bout[nm];
      }
    }
    if (tau==400) break;
    gbar(a.bar, bt);
    // ================= Phase C =================
    {
      int t = tid;
      const f32x4 ev = *(const f32x4*)(a.eP + b4*1024 + t*4);
      float e = ev[0]+ev[1]+ev[2]+ev[3];
      if (!mv) e = -1e9f;
      float mx = e;
      #pragma unroll
      for(int off=1;off<64;off<<=1) mx = fmaxf(mx, __shfl_xor(mx,off));
      if (lan==0) red[wav] = mx;
      __syncthreads();
      mx = fmaxf(fmaxf(red[0],red[1]), fmaxf(red[2],red[3]));
      float pe = __expf(e-mx);
      float sm = pe;
      #pragma unroll
      for(int off=1;off<64;off<<=1) sm += __shfl_xor(sm,off);
      if (lan==0) red[4+wav] = sm;
      __syncthreads();
      sm = red[4]+red[5]+red[6]+red[7];
      float awt = pe/sm;
      if (q4==0){
        a.aw[b4*256+t] = awt;
        a.awc[b4*256+t] += awt;
        a.wout[(size_t)b4*102400 + (size_t)t*400 + tau] = awt;
      }
      sA[t] = awt;
      __syncthreads();
      int fl = tid&127, th = tid>>7;
      const float* xp = a.xin + ((size_t)(b4*256 + th*128))*512 + q4*128 + fl;
      float s=0.f;
      for(int i=0;i<128;i++) s += sA[th*128+i]*xp[(size_t)i*512];
      sA[256+tid] = s;
      __syncthreads();
      if (tid<128){
        float v = sA[256+tid] + sA[384+tid];
        int idx = b4*512 + q4*128 + tid;
        a.ctxf[idx] = v;
        unsigned short hh = f2b(v);
        a.ctxh[idx] = hh;
        a.ctxl[idx] = f2b(v - b2f(hh));
      }
    }
    gbar(a.bar, bt);
  }
}

extern "C" void kernel_launch(void* const* d_in, const int* in_sizes, int n_in,
                              void* d_out, int out_size, void* d_ws, size_t ws_size,
                              hipStream_t stream){
  (void)in_sizes; (void)n_in; (void)out_size; (void)ws_size;
  const float* xin   = (const float*)d_in[0];
  const float* target= (const float*)d_in[2];
  const float* Wpre1 = (const float*)d_in[3];
  const float* bpre1 = (const float*)d_in[4];
  const float* Wpre2 = (const float*)d_in[5];
  const float* bpre2 = (const float*)d_in[6];
  const float* Wq    = (const float*)d_in[7];
  const float* Wk    = (const float*)d_in[8];
  const float* loc_conv = (const float*)d_in[9];
  const float* Wloc  = (const float*)d_in[10];
  const float* v_att = (const float*)d_in[11];
  const float* Wih1  = (const float*)d_in[12];
  const float* Whh1  = (const float*)d_in[13];
  const float* bih1  = (const float*)d_in[14];
  const float* bhh1  = (const float*)d_in[15];
  const float* Wih2  = (const float*)d_in[16];
  const float* Whh2  = (const float*)d_in[17];
  const float* bih2  = (const float*)d_in[18];
  const float* bhh2  = (const float*)d_in[19];
  const float* Wout  = (const float*)d_in[20];
  const float* boutp = (const float*)d_in[21];

  char* w = (char*)d_ws;
  auto carve=[&](size_t bytes)->void*{ void* r=(void*)w; w += (bytes+255)&~(size_t)255; return r; };
  // state region (zeroed every launch) — must stay first & contiguous
  unsigned short* h1h = (unsigned short*)carve((size_t)2*64*1024*2);
  unsigned short* h1l = (unsigned short*)carve((size_t)2*64*1024*2);
  unsigned short* h2h = (unsigned short*)carve((size_t)2*64*1024*2);
  unsigned short* h2l = (unsigned short*)carve((size_t)2*64*1024*2);
  unsigned short* ctxh= (unsigned short*)carve((size_t)64*512*2);
  unsigned short* ctxl= (unsigned short*)carve((size_t)64*512*2);
  float* h1f = (float*)carve((size_t)64*1024*4);
  float* h2f = (float*)carve((size_t)64*1024*4);
  float* ctxf= (float*)carve((size_t)64*512*4);
  float* c1  = (float*)carve((size_t)64*1024*4);
  float* c2  = (float*)carve((size_t)64*1024*4);
  float* aw  = (float*)carve((size_t)64*256*4);
  float* awc = (float*)carve((size_t)64*256*4);
  unsigned* bar = (unsigned*)carve(256);
  int* mflag = (int*)carve(256);
  size_t state_bytes = (size_t)(w - (char*)d_ws);
  float* eP   = (float*)carve((size_t)64*256*4*4);
  float* locT = (float*)carve((size_t)64*32*256*4);
  float* keyp = (float*)carve((size_t)64*256*128*4);
  unsigned short* xbh = (unsigned short*)carve((size_t)400*64*256*2);
  unsigned short* xbl = (unsigned short*)carve((size_t)400*64*256*2);
  float* bsum1 = (float*)carve((size_t)4096*4);
  float* bsum2 = (float*)carve((size_t)4096*4);
  unsigned short* Wp1h = (unsigned short*)carve((size_t)256*56*512*2);
  unsigned short* Wp1l = (unsigned short*)carve((size_t)256*56*512*2);
  unsigned short* Wp2h = (unsigned short*)carve((size_t)256*80*512*2);
  unsigned short* Wp2l = (unsigned short*)carve((size_t)256*80*512*2);

  hipMemsetAsync(d_ws, 0, state_bytes, stream);
  maskdet_k<<<1, 256, 0, stream>>>((const unsigned*)d_in[1], mflag);
  prenet_k<<<400, 256, 0, stream>>>(target, Wpre1, bpre1, Wpre2, bpre2, xbh, xbl);
  keyproj_k<<<1024, 128, 0, stream>>>(xin, Wk, keyp);
  prep_k<<<16, 256, 0, stream>>>(bih1,bhh1,bih2,bhh2,bsum1,bsum2);
  perm_k<<<2048, 256, 0, stream>>>(Wih1,Whh1,Wih2,Whh2,Wp1h,Wp1l,Wp2h,Wp2l);

  SArgs a;
  a.xin=xin; a.loc_conv=loc_conv; a.Wloc=Wloc; a.v_att=v_att; a.bout=boutp;
  a.Wq=Wq; a.Wout=Wout;
  a.keyp=keyp; a.xbh=xbh; a.xbl=xbl;
  a.Wp1h=Wp1h; a.Wp1l=Wp1l; a.Wp2h=Wp2h; a.Wp2l=Wp2l;
  a.bsum1=bsum1; a.bsum2=bsum2;
  a.mask8=(const unsigned char*)d_in[1]; a.mask32=(const int*)d_in[1]; a.mflag=mflag;
  a.h1h=h1h; a.h1l=h1l; a.h1f=h1f;
  a.h2h=h2h; a.h2l=h2l; a.h2f=h2f;
  a.ctxh=ctxh; a.ctxl=ctxl; a.ctxf=ctxf;
  a.c1=c1; a.c2=c2;
  a.aw=aw; a.awc=awc; a.eP=eP; a.locT=locT; a.bar=bar;
  a.outp=(float*)d_out; a.wout=(float*)d_out + (size_t)64*80*400;

  scan_kernel<<<dim3(NB), dim3(NT), 0, stream>>>(a);
}

// Round 13
// 78337.006 us; speedup vs baseline: 4.3178x; 1.0938x over previous
//
#include <hip/hip_runtime.h>

#define NB 256
#define NT 512

typedef __attribute__((ext_vector_type(8))) short short8;
typedef __attribute__((ext_vector_type(4))) float f32x4;

__device__ __forceinline__ float b2f(unsigned short s){ return __uint_as_float(((unsigned)s)<<16); }
__device__ __forceinline__ unsigned short f2b(float f){
  unsigned u = __float_as_uint(f);
  return (unsigned short)((u + 0x7FFFu + ((u>>16)&1u))>>16);
}
__device__ __forceinline__ float sigm(float x){ return 1.0f/(1.0f+__expf(-x)); }
__device__ __forceinline__ float tanh_(float x){ float e=__expf(-2.0f*x); return (1.0f-e)/(1.0f+e); }
__device__ __forceinline__ f32x4 mfma16(short8 a, short8 b, f32x4 c){
  return __builtin_amdgcn_mfma_f32_16x16x32_bf16(a,b,c,0,0,0);
}

__device__ __forceinline__ void gbar(unsigned* bar, unsigned& target){
  __syncthreads();
  if (threadIdx.x==0){
    target += NB;
    __threadfence();
    atomicAdd(bar, 1u);
    while (__hip_atomic_load(bar, __ATOMIC_ACQUIRE, __HIP_MEMORY_SCOPE_AGENT) < target){
      __builtin_amdgcn_s_sleep(1);
    }
    __threadfence();
  }
  __syncthreads();
}

// ---------------- precompute kernels (unchanged from R12) ----------------

__global__ void maskdet_k(const unsigned* __restrict__ m32, int* __restrict__ flag){
  __shared__ int ok;
  if (threadIdx.x==0) ok = 1;
  __syncthreads();
  for (int i=threadIdx.x; i<4096; i+=256){
    if (m32[i] > 1u) ok = 0;
  }
  __syncthreads();
  if (threadIdx.x==0) *flag = ok;
}

__global__ void prenet_k(const float* __restrict__ target, const float* __restrict__ W1, const float* __restrict__ b1,
                         const float* __restrict__ W2, const float* __restrict__ b2,
                         unsigned short* __restrict__ xbh, unsigned short* __restrict__ xbl){
  int t = blockIdx.x;
  int tid = threadIdx.x;
  __shared__ float stgt[64][80];
  __shared__ float smid[64][256];
  for(int i=tid;i<64*80;i+=256){
    int b=i/80, c=i%80;
    stgt[b][c] = (t==0)?0.f : target[((size_t)b*80+c)*400 + (t-1)];
  }
  __syncthreads();
  {
    float w1r[80];
    #pragma unroll
    for(int c=0;c<80;c++) w1r[c] = W1[tid*80+c];
    float bb1 = b1[tid];
    for(int b0=0;b0<64;b0+=16){
      float acc[16];
      #pragma unroll
      for(int i=0;i<16;i++) acc[i]=0.f;
      for(int c=0;c<80;c++){
        float wv=w1r[c];
        #pragma unroll
        for(int i=0;i<16;i++) acc[i] += wv*stgt[b0+i][c];
      }
      #pragma unroll
      for(int i=0;i<16;i++) smid[b0+i][tid] = fmaxf(acc[i]+bb1, 0.f);
    }
  }
  __syncthreads();
  {
    float bb2 = b2[tid];
    for(int b0=0;b0<64;b0+=16){
      float acc[16];
      #pragma unroll
      for(int i=0;i<16;i++) acc[i]=0.f;
      for(int c=0;c<256;c++){
        float wv=W2[tid*256+c];
        #pragma unroll
        for(int i=0;i<16;i++) acc[i] += wv*smid[b0+i][c];
      }
      #pragma unroll
      for(int i=0;i<16;i++){
        float v = fmaxf(acc[i]+bb2,0.f);
        size_t idx = ((size_t)t*64 + b0+i)*256 + tid;
        unsigned short h = f2b(v);
        xbh[idx] = h;
        xbl[idx] = f2b(v - b2f(h));
      }
    }
  }
}

__global__ void keyproj_k(const float* __restrict__ xin, const float* __restrict__ Wk, float* __restrict__ keyp){
  int b = blockIdx.x>>4; int t0=(blockIdx.x&15)*16; int m=threadIdx.x; // 128 threads
  __shared__ float sx[16][512];
  for(int i=m;i<16*512;i+=128){ int tt=i>>9, f=i&511; sx[tt][f]=xin[((size_t)b*256+t0+tt)*512+f]; }
  __syncthreads();
  float s[16];
  #pragma unroll
  for(int i=0;i<16;i++) s[i]=0.f;
  for(int f=0;f<512;f++){
    float wv = Wk[m*512+f];
    #pragma unroll
    for(int i=0;i<16;i++) s[i]+=sx[i][f]*wv;
  }
  #pragma unroll
  for(int i=0;i<16;i++) keyp[((size_t)b*256+t0+i)*128+m]=s[i];
}

__global__ void prep_k(const float* bih1,const float* bhh1,const float* bih2,const float* bhh2,
                       float* bsum1,float* bsum2){
  int i0 = blockIdx.x*blockDim.x + threadIdx.x;
  int n = gridDim.x*blockDim.x;
  for(int k=i0;k<4096;k+=n){ bsum1[k]=bih1[k]+bhh1[k]; bsum2[k]=bih2[k]+bhh2[k]; }
}

__global__ void perm_k(const float* __restrict__ Wih1, const float* __restrict__ Whh1,
                       const float* __restrict__ Wih2, const float* __restrict__ Whh2,
                       unsigned short* __restrict__ Wp1h, unsigned short* __restrict__ Wp1l,
                       unsigned short* __restrict__ Wp2h, unsigned short* __restrict__ Wp2l){
  size_t i0 = (size_t)blockIdx.x*blockDim.x + threadIdx.x;
  size_t n  = (size_t)gridDim.x*blockDim.x;
  const size_t N1 = (size_t)256*56*512;
  for(size_t idx=i0; idx<N1; idx+=n){
    int beta = (int)(idx/28672);
    int r = (int)(idx%28672);
    int kt = r/512;
    int l  = (r>>3)&63;
    int i8 = r&7;
    int c = l&15, cci = l>>4;
    int k = kt*32 + cci*8 + i8;
    int rowp = (c>>2)*1024 + beta*4 + (c&3);
    float v = (k<768)? Wih1[(size_t)rowp*768 + k] : Whh1[(size_t)rowp*1024 + (k-768)];
    unsigned short h = f2b(v);
    Wp1h[idx] = h;
    Wp1l[idx] = f2b(v - b2f(h));
  }
  const size_t N2 = (size_t)256*80*512;
  for(size_t idx=i0; idx<N2; idx+=n){
    int beta = (int)(idx/40960);
    int r = (int)(idx%40960);
    int kt = r/512;
    int l  = (r>>3)&63;
    int i8 = r&7;
    int c = l&15, cci = l>>4;
    int k = kt*32 + cci*8 + i8;
    int rowp = (c>>2)*1024 + beta*4 + (c&3);
    float v = (k<1536)? Wih2[(size_t)rowp*1536 + k] : Whh2[(size_t)rowp*1024 + (k-1536)];
    unsigned short h = f2b(v);
    Wp2h[idx] = h;
    Wp2l[idx] = f2b(v - b2f(h));
  }
}

// ---------------- the scan (persistent; 512 threads: LSTM1 ∥ LSTM2) ----------------

struct SArgs {
  const float* xin; const float* loc_conv; const float* Wloc; const float* v_att; const float* bout;
  const float* Wq; const float* Wout;
  const float* keyp;
  const unsigned short* xbh; const unsigned short* xbl;
  const unsigned short* Wp1h; const unsigned short* Wp1l;
  const unsigned short* Wp2h; const unsigned short* Wp2l;
  const float* bsum1; const float* bsum2;
  const unsigned char* mask8; const int* mask32; const int* mflag;
  unsigned short* h1h; unsigned short* h1l; float* h1f;
  unsigned short* h2h; unsigned short* h2l; float* h2f;
  unsigned short* ctxh; unsigned short* ctxl; float* ctxf;
  float* c1; float* c2;
  float* aw; float* awc; float* eP; float* locT;
  unsigned* bar;
  float* outp; float* wout;
};

__global__ void __launch_bounds__(NT) scan_kernel(SArgs a){
  const int beta = blockIdx.x;
  const int tid = threadIdx.x;
  const int wav = tid>>6;
  const int lan = tid&63;

  __shared__ float gsc1[64][17];
  __shared__ float gsc2[64][17];
  __shared__ float sA[2560];
  __shared__ float sq[32];
  __shared__ float sv[32];
  __shared__ float red[8];

  const int cc  = lan>>4;
  const int b4  = beta>>2;
  const int q4  = beta&3;
  unsigned bt = 0;

  bool mv = false;
  if (tid<256) mv = (a.mflag[0] ? (a.mask32[b4*256+tid] != 0) : (a.mask8[b4*256+tid] != 0));

  for (int tau=0; tau<=400; ++tau){
    const int p = tau&1;
    // ================= Phase A: LSTM1 (waves 0-3) ∥ LSTM2 (waves 4-7) =================
    if (tau<400 && wav<4){
      // LSTM1 gates, step tau: X = [xb_tau | ctx_{tau-1} | h1_{tau-1}], K=1792
      const int row = wav*16 + (lan&15);
      f32x4 A0={0.f,0.f,0.f,0.f}, A1={0.f,0.f,0.f,0.f}, A2={0.f,0.f,0.f,0.f};
      const unsigned short* wh = a.Wp1h + (size_t)beta*28672 + lan*8;
      const unsigned short* wl = a.Wp1l + (size_t)beta*28672 + lan*8;
      {
        const unsigned short* xh = a.xbh + ((size_t)tau*64 + row)*256 + cc*8;
        const unsigned short* xl = a.xbl + ((size_t)tau*64 + row)*256 + cc*8;
        #pragma unroll
        for(int kt=0;kt<8;kt++){
          short8 ah=*(const short8*)(xh+kt*32), al=*(const short8*)(xl+kt*32);
          short8 bh=*(const short8*)(wh+kt*512), bl=*(const short8*)(wl+kt*512);
          A0=mfma16(ah,bh,A0); A1=mfma16(ah,bl,A1); A2=mfma16(al,bh,A2);
        }
      }
      {
        const unsigned short* xh = a.ctxh + row*512 + cc*8;
        const unsigned short* xl = a.ctxl + row*512 + cc*8;
        #pragma unroll 4
        for(int kt=8;kt<24;kt++){
          short8 ah=*(const short8*)(xh+(kt-8)*32), al=*(const short8*)(xl+(kt-8)*32);
          short8 bh=*(const short8*)(wh+kt*512), bl=*(const short8*)(wl+kt*512);
          A0=mfma16(ah,bh,A0); A1=mfma16(ah,bl,A1); A2=mfma16(al,bh,A2);
        }
      }
      {
        const unsigned short* xh = a.h1h + (size_t)(p^1)*65536 + row*1024 + cc*8;
        const unsigned short* xl = a.h1l + (size_t)(p^1)*65536 + row*1024 + cc*8;
        #pragma unroll 4
        for(int kt=24;kt<56;kt++){
          short8 ah=*(const short8*)(xh+(kt-24)*32), al=*(const short8*)(xl+(kt-24)*32);
          short8 bh=*(const short8*)(wh+kt*512), bl=*(const short8*)(wl+kt*512);
          A0=mfma16(ah,bh,A0); A1=mfma16(ah,bl,A1); A2=mfma16(al,bh,A2);
        }
      }
      #pragma unroll
      for(int r=0;r<4;r++) gsc1[wav*16 + cc*4 + r][lan&15] = A0[r]+A1[r]+A2[r];
    }
    if (tau>0 && wav>=4){
      // LSTM2 gates, step tau-1: X = [h1_{tau-1} | ctx_{tau-1} | h2_{tau-2}], K=2560
      const int wv2 = wav-4;
      const int row = wv2*16 + (lan&15);
      f32x4 A0={0.f,0.f,0.f,0.f}, A1={0.f,0.f,0.f,0.f}, A2={0.f,0.f,0.f,0.f};
      const unsigned short* wh = a.Wp2h + (size_t)beta*40960 + lan*8;
      const unsigned short* wl = a.Wp2l + (size_t)beta*40960 + lan*8;
      {
        const unsigned short* xh = a.h1h + (size_t)(p^1)*65536 + row*1024 + cc*8;
        const unsigned short* xl = a.h1l + (size_t)(p^1)*65536 + row*1024 + cc*8;
        #pragma unroll 4
        for(int kt=0;kt<32;kt++){
          short8 ah=*(const short8*)(xh+kt*32), al=*(const short8*)(xl+kt*32);
          short8 bh=*(const short8*)(wh+kt*512), bl=*(const short8*)(wl+kt*512);
          A0=mfma16(ah,bh,A0); A1=mfma16(ah,bl,A1); A2=mfma16(al,bh,A2);
        }
      }
      {
        const unsigned short* xh = a.ctxh + row*512 + cc*8;
        const unsigned short* xl = a.ctxl + row*512 + cc*8;
        #pragma unroll 4
        for(int kt=32;kt<48;kt++){
          short8 ah=*(const short8*)(xh+(kt-32)*32), al=*(const short8*)(xl+(kt-32)*32);
          short8 bh=*(const short8*)(wh+kt*512), bl=*(const short8*)(wl+kt*512);
          A0=mfma16(ah,bh,A0); A1=mfma16(ah,bl,A1); A2=mfma16(al,bh,A2);
        }
      }
      {
        const unsigned short* xh = a.h2h + (size_t)p*65536 + row*1024 + cc*8;
        const unsigned short* xl = a.h2l + (size_t)p*65536 + row*1024 + cc*8;
        #pragma unroll 4
        for(int kt=48;kt<80;kt++){
          short8 ah=*(const short8*)(xh+(kt-48)*32), al=*(const short8*)(xl+(kt-48)*32);
          short8 bh=*(const short8*)(wh+kt*512), bl=*(const short8*)(wl+kt*512);
          A0=mfma16(ah,bh,A0); A1=mfma16(ah,bl,A1); A2=mfma16(al,bh,A2);
        }
      }
      #pragma unroll
      for(int r=0;r<4;r++) gsc2[wv2*16 + cc*4 + r][lan&15] = A0[r]+A1[r]+A2[r];
    }
    __syncthreads();
    if (tau<400 && tid<256){
      int m = tid>>2, j = tid&3, u = beta*4+j;
      float gi = gsc1[m][0+j]  + a.bsum1[0*1024+u];
      float gf = gsc1[m][4+j]  + a.bsum1[1*1024+u];
      float gg = gsc1[m][8+j]  + a.bsum1[2*1024+u];
      float go = gsc1[m][12+j] + a.bsum1[3*1024+u];
      float cp = a.c1[m*1024+u];
      float cn = sigm(gf)*cp + sigm(gi)*tanh_(gg);
      a.c1[m*1024+u] = cn;
      float hn = sigm(go)*tanh_(cn);
      a.h1f[m*1024+u] = hn;
      unsigned short hh = f2b(hn);
      a.h1h[(size_t)p*65536 + m*1024 + u] = hh;
      a.h1l[(size_t)p*65536 + m*1024 + u] = f2b(hn - b2f(hh));
    }
    if (tau>0 && tid>=256){
      int t2 = tid-256;
      int m = t2>>2, j = t2&3, u = beta*4+j;
      float gi = gsc2[m][0+j]  + a.bsum2[0*1024+u];
      float gf = gsc2[m][4+j]  + a.bsum2[1*1024+u];
      float gg = gsc2[m][8+j]  + a.bsum2[2*1024+u];
      float go = gsc2[m][12+j] + a.bsum2[3*1024+u];
      float cp = a.c2[m*1024+u];
      float cn = sigm(gf)*cp + sigm(gi)*tanh_(gg);
      a.c2[m*1024+u] = cn;
      float hn = sigm(go)*tanh_(cn);
      a.h2f[m*1024+u] = hn;
      unsigned short hh = f2b(hn);
      a.h2h[(size_t)(p^1)*65536 + m*1024 + u] = hh;
      a.h2l[(size_t)(p^1)*65536 + m*1024 + u] = f2b(hn - b2f(hh));
    }
    if (tau<400){
      // location features for step tau (uses aw_{tau-1}, awc_{tau-1})
      for(int i=tid;i<256;i+=NT){ sA[i] = a.aw[b4*256+i]; sA[256+i] = a.awc[b4*256+i]; }
      for(int i=tid;i<1984;i+=NT) sA[512+i] = a.loc_conv[i];
    }
    __syncthreads();
    if (tau<400){
      const int t0 = q4*64;
      #pragma unroll
      for(int jj=0;jj<4;jj++){
        int o = tid*4+jj;           // 2048 outputs across 512 threads
        int f = o>>6, tl = o&63, t = t0+tl;
        float s = 0.f;
        #pragma unroll
        for(int c=0;c<2;c++){
          const float* kw = &sA[512 + (f*2+c)*31];
          const float* wv = &sA[c*256];
          for(int k=0;k<31;k++){
            int tt = t + k - 15;
            if (tt>=0 && tt<256) s += wv[tt]*kw[k];
          }
        }
        a.locT[(size_t)b4*8192 + f*256 + t] = s;
      }
    }
    gbar(a.bar, bt);
    // ================= Phase B: q/e path (tid<256) ∥ out-proj (tid 256-415) =================
    if (tau<400 && tid<256){
      for(int i=tid;i<1024;i+=256) sA[i] = a.h1f[b4*1024 + i];
    }
    if (tau>0 && tid>=256){
      int t2 = tid-256;
      for(int i=t2;i<1024;i+=256) sA[1024+i] = a.h2f[b4*1024 + i];
      for(int i=t2;i<512;i+=256)  sA[2048+i] = a.ctxf[b4*512 + i];
    }
    __syncthreads();
    if (tau<400 && tid<256){
      int ml = tid>>3, sg = tid&7;
      const float* wq = a.Wq + (size_t)(q4*32+ml)*1024;
      float s=0.f;
      #pragma unroll 8
      for(int i=0;i<128;i++) s += sA[sg + i*8]*wq[sg + i*8];
      s += __shfl_xor(s,1); s += __shfl_xor(s,2); s += __shfl_xor(s,4);
      if (sg==0) sq[ml] = s;
    }
    if (tau>0 && tid>=256 && tid<416){
      int t2 = tid-256;
      int nl = t2>>3, sg = t2&7, nm = q4*20+nl;
      const float* wo = a.Wout + (size_t)nm*1536;
      float s=0.f;
      #pragma unroll 8
      for(int i=0;i<192;i++) s += sA[1024 + sg + i*8]*wo[sg + i*8];
      s += __shfl_xor(s,1); s += __shfl_xor(s,2); s += __shfl_xor(s,4);
      if (sg==0) a.outp[(size_t)b4*32000 + nm*400 + (tau-1)] = s + a.bout[nm];
    }
    __syncthreads();
    if (tau<400 && tid<256){
      for(int i=tid;i<1024;i+=256) sA[i] = a.Wloc[(q4*32 + (i>>5))*32 + (i&31)];
    }
    if (tid<32) sv[tid] = a.v_att[q4*32+tid];
    __syncthreads();
    if (tau<400 && tid<256){
      int t = tid;
      float lc[32];
      const float* lb = a.locT + (size_t)b4*8192 + t;
      #pragma unroll
      for(int f=0;f<32;f++) lc[f] = lb[f*256];
      const float* kb = a.keyp + ((size_t)b4*256 + t)*128 + q4*32;
      float acc=0.f;
      for(int mm=0;mm<32;mm++){
        float lf=0.f;
        #pragma unroll
        for(int f=0;f<32;f++) lf += lc[f]*sA[mm*32+f];
        acc += tanh_(sq[mm] + kb[mm] + lf)*sv[mm];
      }
      a.eP[b4*1024 + t*4 + q4] = acc;
    }
    if (tau==400) break;
    gbar(a.bar, bt);
    // ================= Phase C =================
    {
      float e=0.f, pe=0.f, mx=0.f;
      if (tid<256){
        const f32x4 ev = *(const f32x4*)(a.eP + b4*1024 + tid*4);
        e = ev[0]+ev[1]+ev[2]+ev[3];
        if (!mv) e = -1e9f;
        mx = e;
        #pragma unroll
        for(int off=1;off<64;off<<=1) mx = fmaxf(mx, __shfl_xor(mx,off));
        if (lan==0) red[wav] = mx;
      }
      __syncthreads();
      if (tid<256){
        mx = fmaxf(fmaxf(red[0],red[1]), fmaxf(red[2],red[3]));
        pe = __expf(e-mx);
        float sm = pe;
        #pragma unroll
        for(int off=1;off<64;off<<=1) sm += __shfl_xor(sm,off);
        if (lan==0) red[4+wav] = sm;
      }
      __syncthreads();
      if (tid<256){
        float sm = red[4]+red[5]+red[6]+red[7];
        float awt = pe/sm;
        if (q4==0){
          a.aw[b4*256+tid] = awt;
          a.awc[b4*256+tid] += awt;
          a.wout[(size_t)b4*102400 + (size_t)tid*400 + tau] = awt;
        }
        sA[tid] = awt;
      }
      __syncthreads();
      {
        int fl = tid&127, th = tid>>7;   // th in 0..3, 64 rows each
        const float* xp = a.xin + ((size_t)(b4*256 + th*64))*512 + q4*128 + fl;
        float s=0.f;
        for(int i=0;i<64;i++) s += sA[th*64+i]*xp[(size_t)i*512];
        sA[256+tid] = s;
      }
      __syncthreads();
      if (tid<128){
        float v = sA[256+tid] + sA[384+tid] + sA[512+tid] + sA[640+tid];
        int idx = b4*512 + q4*128 + tid;
        a.ctxf[idx] = v;
        unsigned short hh = f2b(v);
        a.ctxh[idx] = hh;
        a.ctxl[idx] = f2b(v - b2f(hh));
      }
    }
    gbar(a.bar, bt);
  }
}

extern "C" void kernel_launch(void* const* d_in, const int* in_sizes, int n_in,
                              void* d_out, int out_size, void* d_ws, size_t ws_size,
                              hipStream_t stream){
  (void)in_sizes; (void)n_in; (void)out_size; (void)ws_size;
  const float* xin   = (const float*)d_in[0];
  const float* target= (const float*)d_in[2];
  const float* Wpre1 = (const float*)d_in[3];
  const float* bpre1 = (const float*)d_in[4];
  const float* Wpre2 = (const float*)d_in[5];
  const float* bpre2 = (const float*)d_in[6];
  const float* Wq    = (const float*)d_in[7];
  const float* Wk    = (const float*)d_in[8];
  const float* loc_conv = (const float*)d_in[9];
  const float* Wloc  = (const float*)d_in[10];
  const float* v_att = (const float*)d_in[11];
  const float* Wih1  = (const float*)d_in[12];
  const float* Whh1  = (const float*)d_in[13];
  const float* bih1  = (const float*)d_in[14];
  const float* bhh1  = (const float*)d_in[15];
  const float* Wih2  = (const float*)d_in[16];
  const float* Whh2  = (const float*)d_in[17];
  const float* bih2  = (const float*)d_in[18];
  const float* bhh2  = (const float*)d_in[19];
  const float* Wout  = (const float*)d_in[20];
  const float* boutp = (const float*)d_in[21];

  char* w = (char*)d_ws;
  auto carve=[&](size_t bytes)->void*{ void* r=(void*)w; w += (bytes+255)&~(size_t)255; return r; };
  // state region (zeroed every launch) — must stay first & contiguous
  unsigned short* h1h = (unsigned short*)carve((size_t)2*64*1024*2);
  unsigned short* h1l = (unsigned short*)carve((size_t)2*64*1024*2);
  unsigned short* h2h = (unsigned short*)carve((size_t)2*64*1024*2);
  unsigned short* h2l = (unsigned short*)carve((size_t)2*64*1024*2);
  unsigned short* ctxh= (unsigned short*)carve((size_t)64*512*2);
  unsigned short* ctxl= (unsigned short*)carve((size_t)64*512*2);
  float* h1f = (float*)carve((size_t)64*1024*4);
  float* h2f = (float*)carve((size_t)64*1024*4);
  float* ctxf= (float*)carve((size_t)64*512*4);
  float* c1  = (float*)carve((size_t)64*1024*4);
  float* c2  = (float*)carve((size_t)64*1024*4);
  float* aw  = (float*)carve((size_t)64*256*4);
  float* awc = (float*)carve((size_t)64*256*4);
  unsigned* bar = (unsigned*)carve(256);
  int* mflag = (int*)carve(256);
  size_t state_bytes = (size_t)(w - (char*)d_ws);
  float* eP   = (float*)carve((size_t)64*256*4*4);
  float* locT = (float*)carve((size_t)64*32*256*4);
  float* keyp = (float*)carve((size_t)64*256*128*4);
  unsigned short* xbh = (unsigned short*)carve((size_t)400*64*256*2);
  unsigned short* xbl = (unsigned short*)carve((size_t)400*64*256*2);
  float* bsum1 = (float*)carve((size_t)4096*4);
  float* bsum2 = (float*)carve((size_t)4096*4);
  unsigned short* Wp1h = (unsigned short*)carve((size_t)256*56*512*2);
  unsigned short* Wp1l = (unsigned short*)carve((size_t)256*56*512*2);
  unsigned short* Wp2h = (unsigned short*)carve((size_t)256*80*512*2);
  unsigned short* Wp2l = (unsigned short*)carve((size_t)256*80*512*2);

  hipMemsetAsync(d_ws, 0, state_bytes, stream);
  maskdet_k<<<1, 256, 0, stream>>>((const unsigned*)d_in[1], mflag);
  prenet_k<<<400, 256, 0, stream>>>(target, Wpre1, bpre1, Wpre2, bpre2, xbh, xbl);
  keyproj_k<<<1024, 128, 0, stream>>>(xin, Wk, keyp);
  prep_k<<<16, 256, 0, stream>>>(bih1,bhh1,bih2,bhh2,bsum1,bsum2);
  perm_k<<<2048, 256, 0, stream>>>(Wih1,Whh1,Wih2,Whh2,Wp1h,Wp1l,Wp2h,Wp2l);

  SArgs a;
  a.xin=xin; a.loc_conv=loc_conv; a.Wloc=Wloc; a.v_att=v_att; a.bout=boutp;
  a.Wq=Wq; a.Wout=Wout;
  a.keyp=keyp; a.xbh=xbh; a.xbl=xbl;
  a.Wp1h=Wp1h; a.Wp1l=Wp1l; a.Wp2h=Wp2h; a.Wp2l=Wp2l;
  a.bsum1=bsum1; a.bsum2=bsum2;
  a.mask8=(const unsigned char*)d_in[1]; a.mask32=(const int*)d_in[1]; a.mflag=mflag;
  a.h1h=h1h; a.h1l=h1l; a.h1f=h1f;
  a.h2h=h2h; a.h2l=h2l; a.h2f=h2f;
  a.ctxh=ctxh; a.ctxl=ctxl; a.ctxf=ctxf;
  a.c1=c1; a.c2=c2;
  a.aw=aw; a.awc=awc; a.eP=eP; a.locT=locT; a.bar=bar;
  a.outp=(float*)d_out; a.wout=(float*)d_out + (size_t)64*80*400;

  scan_kernel<<<dim3(NB), dim3(NT), 0, stream>>>(a);
}

// Round 14
// 72000.836 us; speedup vs baseline: 4.6978x; 1.0880x over previous
//
#include <hip/hip_runtime.h>

#define NB 256
#define NT 512

typedef __attribute__((ext_vector_type(8))) short short8;
typedef __attribute__((ext_vector_type(4))) float f32x4;

__device__ __forceinline__ float b2f(unsigned short s){ return __uint_as_float(((unsigned)s)<<16); }
__device__ __forceinline__ unsigned short f2b(float f){
  unsigned u = __float_as_uint(f);
  return (unsigned short)((u + 0x7FFFu + ((u>>16)&1u))>>16);
}
__device__ __forceinline__ float sigm(float x){ return 1.0f/(1.0f+__expf(-x)); }
__device__ __forceinline__ float tanh_(float x){ float e=__expf(-2.0f*x); return (1.0f-e)/(1.0f+e); }
__device__ __forceinline__ f32x4 mfma16(short8 a, short8 b, f32x4 c){
  return __builtin_amdgcn_mfma_f32_16x16x32_bf16(a,b,c,0,0,0);
}

__device__ __forceinline__ void gbar(unsigned* bar, unsigned& target){
  __syncthreads();
  if (threadIdx.x==0){
    target += NB;
    __threadfence();
    atomicAdd(bar, 1u);
    while (__hip_atomic_load(bar, __ATOMIC_ACQUIRE, __HIP_MEMORY_SCOPE_AGENT) < target){
      __builtin_amdgcn_s_sleep(1);
    }
    __threadfence();
  }
  __syncthreads();
}

// ---------------- precompute kernels ----------------

__global__ void maskdet_k(const unsigned* __restrict__ m32, int* __restrict__ flag){
  __shared__ int ok;
  if (threadIdx.x==0) ok = 1;
  __syncthreads();
  for (int i=threadIdx.x; i<4096; i+=256){
    if (m32[i] > 1u) ok = 0;
  }
  __syncthreads();
  if (threadIdx.x==0) *flag = ok;
}

__global__ void prenet_k(const float* __restrict__ target, const float* __restrict__ W1, const float* __restrict__ b1,
                         const float* __restrict__ W2, const float* __restrict__ b2,
                         unsigned short* __restrict__ xbh){
  int t = blockIdx.x;
  int tid = threadIdx.x;
  __shared__ float stgt[64][80];
  __shared__ float smid[64][256];
  for(int i=tid;i<64*80;i+=256){
    int b=i/80, c=i%80;
    stgt[b][c] = (t==0)?0.f : target[((size_t)b*80+c)*400 + (t-1)];
  }
  __syncthreads();
  {
    float w1r[80];
    #pragma unroll
    for(int c=0;c<80;c++) w1r[c] = W1[tid*80+c];
    float bb1 = b1[tid];
    for(int b0=0;b0<64;b0+=16){
      float acc[16];
      #pragma unroll
      for(int i=0;i<16;i++) acc[i]=0.f;
      for(int c=0;c<80;c++){
        float wv=w1r[c];
        #pragma unroll
        for(int i=0;i<16;i++) acc[i] += wv*stgt[b0+i][c];
      }
      #pragma unroll
      for(int i=0;i<16;i++) smid[b0+i][tid] = fmaxf(acc[i]+bb1, 0.f);
    }
  }
  __syncthreads();
  {
    float bb2 = b2[tid];
    for(int b0=0;b0<64;b0+=16){
      float acc[16];
      #pragma unroll
      for(int i=0;i<16;i++) acc[i]=0.f;
      for(int c=0;c<256;c++){
        float wv=W2[tid*256+c];
        #pragma unroll
        for(int i=0;i<16;i++) acc[i] += wv*smid[b0+i][c];
      }
      #pragma unroll
      for(int i=0;i<16;i++){
        float v = fmaxf(acc[i]+bb2,0.f);
        xbh[((size_t)t*64 + b0+i)*256 + tid] = f2b(v);
      }
    }
  }
}

__global__ void keyproj_k(const float* __restrict__ xin, const float* __restrict__ Wk, float* __restrict__ keyp){
  int b = blockIdx.x>>4; int t0=(blockIdx.x&15)*16; int m=threadIdx.x; // 128 threads
  __shared__ float sx[16][512];
  for(int i=m;i<16*512;i+=128){ int tt=i>>9, f=i&511; sx[tt][f]=xin[((size_t)b*256+t0+tt)*512+f]; }
  __syncthreads();
  float s[16];
  #pragma unroll
  for(int i=0;i<16;i++) s[i]=0.f;
  for(int f=0;f<512;f++){
    float wv = Wk[m*512+f];
    #pragma unroll
    for(int i=0;i<16;i++) s[i]+=sx[i][f]*wv;
  }
  #pragma unroll
  for(int i=0;i<16;i++) keyp[((size_t)b*256+t0+i)*128+m]=s[i];
}

__global__ void prep_k(const float* bih1,const float* bhh1,const float* bih2,const float* bhh2,
                       float* bsum1,float* bsum2){
  int i0 = blockIdx.x*blockDim.x + threadIdx.x;
  int n = gridDim.x*blockDim.x;
  for(int k=i0;k<4096;k+=n){ bsum1[k]=bih1[k]+bhh1[k]; bsum2[k]=bih2[k]+bhh2[k]; }
}

__global__ void perm_k(const float* __restrict__ Wih1, const float* __restrict__ Whh1,
                       const float* __restrict__ Wih2, const float* __restrict__ Whh2,
                       unsigned short* __restrict__ Wp1h, unsigned short* __restrict__ Wp2h){
  size_t i0 = (size_t)blockIdx.x*blockDim.x + threadIdx.x;
  size_t n  = (size_t)gridDim.x*blockDim.x;
  const size_t N1 = (size_t)256*56*512;
  for(size_t idx=i0; idx<N1; idx+=n){
    int beta = (int)(idx/28672);
    int r = (int)(idx%28672);
    int kt = r/512;
    int l  = (r>>3)&63;
    int i8 = r&7;
    int c = l&15, cci = l>>4;
    int k = kt*32 + cci*8 + i8;
    int rowp = (c>>2)*1024 + beta*4 + (c&3);
    float v = (k<768)? Wih1[(size_t)rowp*768 + k] : Whh1[(size_t)rowp*1024 + (k-768)];
    Wp1h[idx] = f2b(v);
  }
  const size_t N2 = (size_t)256*80*512;
  for(size_t idx=i0; idx<N2; idx+=n){
    int beta = (int)(idx/40960);
    int r = (int)(idx%40960);
    int kt = r/512;
    int l  = (r>>3)&63;
    int i8 = r&7;
    int c = l&15, cci = l>>4;
    int k = kt*32 + cci*8 + i8;
    int rowp = (c>>2)*1024 + beta*4 + (c&3);
    float v = (k<1536)? Wih2[(size_t)rowp*1536 + k] : Whh2[(size_t)rowp*1024 + (k-1536)];
    Wp2h[idx] = f2b(v);
  }
}

// ---------------- the scan (persistent; 512 threads; hi-only bf16 operands) ----------------

struct SArgs {
  const float* xin; const float* loc_conv; const float* Wloc; const float* v_att; const float* bout;
  const float* Wq; const float* Wout;
  const float* keyp;
  const unsigned short* xbh;
  const unsigned short* Wp1h; const unsigned short* Wp2h;
  const float* bsum1; const float* bsum2;
  const unsigned char* mask8; const int* mask32; const int* mflag;
  unsigned short* h1h; float* h1f;
  unsigned short* h2h; float* h2f;
  unsigned short* ctxh; float* ctxf;
  float* c1; float* c2;
  float* aw; float* awc; float* eP; float* locT;
  unsigned* bar;
  float* outp; float* wout;
};

__global__ void __launch_bounds__(NT) scan_kernel(SArgs a){
  const int beta = blockIdx.x;
  const int tid = threadIdx.x;
  const int wav = tid>>6;
  const int lan = tid&63;

  __shared__ float gsc1[64][17];
  __shared__ float gsc2[64][17];
  __shared__ float sA[2560];
  __shared__ float sq[32];
  __shared__ float sv[32];
  __shared__ float red[8];

  const int cc  = lan>>4;
  const int b4  = beta>>2;
  const int q4  = beta&3;
  unsigned bt = 0;

  bool mv = false;
  if (tid<256) mv = (a.mflag[0] ? (a.mask32[b4*256+tid] != 0) : (a.mask8[b4*256+tid] != 0));

  for (int tau=0; tau<=400; ++tau){
    const int p = tau&1;
    // ================= Phase A: LSTM1 (waves 0-3) ∥ LSTM2 (waves 4-7) =================
    if (tau<400 && wav<4){
      // LSTM1 gates, step tau: X = [xb_tau | ctx_{tau-1} | h1_{tau-1}], K=1792
      const int row = wav*16 + (lan&15);
      f32x4 A0={0.f,0.f,0.f,0.f};
      const unsigned short* wh = a.Wp1h + (size_t)beta*28672 + lan*8;
      {
        const unsigned short* xh = a.xbh + ((size_t)tau*64 + row)*256 + cc*8;
        #pragma unroll
        for(int kt=0;kt<8;kt++)
          A0=mfma16(*(const short8*)(xh+kt*32), *(const short8*)(wh+kt*512), A0);
      }
      {
        const unsigned short* xh = a.ctxh + row*512 + cc*8;
        #pragma unroll 8
        for(int kt=8;kt<24;kt++)
          A0=mfma16(*(const short8*)(xh+(kt-8)*32), *(const short8*)(wh+kt*512), A0);
      }
      {
        const unsigned short* xh = a.h1h + (size_t)(p^1)*65536 + row*1024 + cc*8;
        #pragma unroll 8
        for(int kt=24;kt<56;kt++)
          A0=mfma16(*(const short8*)(xh+(kt-24)*32), *(const short8*)(wh+kt*512), A0);
      }
      #pragma unroll
      for(int r=0;r<4;r++) gsc1[wav*16 + cc*4 + r][lan&15] = A0[r];
    }
    if (tau>0 && wav>=4){
      // LSTM2 gates, step tau-1: X = [h1_{tau-1} | ctx_{tau-1} | h2_{tau-2}], K=2560
      const int wv2 = wav-4;
      const int row = wv2*16 + (lan&15);
      f32x4 A0={0.f,0.f,0.f,0.f};
      const unsigned short* wh = a.Wp2h + (size_t)beta*40960 + lan*8;
      {
        const unsigned short* xh = a.h1h + (size_t)(p^1)*65536 + row*1024 + cc*8;
        #pragma unroll 8
        for(int kt=0;kt<32;kt++)
          A0=mfma16(*(const short8*)(xh+kt*32), *(const short8*)(wh+kt*512), A0);
      }
      {
        const unsigned short* xh = a.ctxh + row*512 + cc*8;
        #pragma unroll 8
        for(int kt=32;kt<48;kt++)
          A0=mfma16(*(const short8*)(xh+(kt-32)*32), *(const short8*)(wh+kt*512), A0);
      }
      {
        const unsigned short* xh = a.h2h + (size_t)p*65536 + row*1024 + cc*8;
        #pragma unroll 8
        for(int kt=48;kt<80;kt++)
          A0=mfma16(*(const short8*)(xh+(kt-48)*32), *(const short8*)(wh+kt*512), A0);
      }
      #pragma unroll
      for(int r=0;r<4;r++) gsc2[wv2*16 + cc*4 + r][lan&15] = A0[r];
    }
    __syncthreads();
    if (tau<400 && tid<256){
      int m = tid>>2, j = tid&3, u = beta*4+j;
      float gi = gsc1[m][0+j]  + a.bsum1[0*1024+u];
      float gf = gsc1[m][4+j]  + a.bsum1[1*1024+u];
      float gg = gsc1[m][8+j]  + a.bsum1[2*1024+u];
      float go = gsc1[m][12+j] + a.bsum1[3*1024+u];
      float cp = a.c1[m*1024+u];
      float cn = sigm(gf)*cp + sigm(gi)*tanh_(gg);
      a.c1[m*1024+u] = cn;
      float hn = sigm(go)*tanh_(cn);
      a.h1f[m*1024+u] = hn;
      a.h1h[(size_t)p*65536 + m*1024 + u] = f2b(hn);
    }
    if (tau>0 && tid>=256){
      int t2 = tid-256;
      int m = t2>>2, j = t2&3, u = beta*4+j;
      float gi = gsc2[m][0+j]  + a.bsum2[0*1024+u];
      float gf = gsc2[m][4+j]  + a.bsum2[1*1024+u];
      float gg = gsc2[m][8+j]  + a.bsum2[2*1024+u];
      float go = gsc2[m][12+j] + a.bsum2[3*1024+u];
      float cp = a.c2[m*1024+u];
      float cn = sigm(gf)*cp + sigm(gi)*tanh_(gg);
      a.c2[m*1024+u] = cn;
      float hn = sigm(go)*tanh_(cn);
      a.h2f[m*1024+u] = hn;
      a.h2h[(size_t)(p^1)*65536 + m*1024 + u] = f2b(hn);
    }
    if (tau<400){
      // location features for step tau (uses aw_{tau-1}, awc_{tau-1})
      for(int i=tid;i<256;i+=NT){ sA[i] = a.aw[b4*256+i]; sA[256+i] = a.awc[b4*256+i]; }
      for(int i=tid;i<1984;i+=NT) sA[512+i] = a.loc_conv[i];
    }
    __syncthreads();
    if (tau<400){
      const int t0 = q4*64;
      #pragma unroll
      for(int jj=0;jj<4;jj++){
        int o = tid*4+jj;           // 2048 outputs across 512 threads
        int f = o>>6, tl = o&63, t = t0+tl;
        float s = 0.f;
        #pragma unroll
        for(int c=0;c<2;c++){
          const float* kw = &sA[512 + (f*2+c)*31];
          const float* wv = &sA[c*256];
          for(int k=0;k<31;k++){
            int tt = t + k - 15;
            if (tt>=0 && tt<256) s += wv[tt]*kw[k];
          }
        }
        a.locT[(size_t)b4*8192 + f*256 + t] = s;
      }
    }
    gbar(a.bar, bt);
    // ================= Phase B: q/e path (tid<256) ∥ out-proj (tid 256-415) =================
    if (tau<400 && tid<256){
      for(int i=tid;i<1024;i+=256) sA[i] = a.h1f[b4*1024 + i];
    }
    if (tau>0 && tid>=256){
      int t2 = tid-256;
      for(int i=t2;i<1024;i+=256) sA[1024+i] = a.h2f[b4*1024 + i];
      for(int i=t2;i<512;i+=256)  sA[2048+i] = a.ctxf[b4*512 + i];
    }
    __syncthreads();
    if (tau<400 && tid<256){
      int ml = tid>>3, sg = tid&7;
      const float* wq = a.Wq + (size_t)(q4*32+ml)*1024;
      float s=0.f;
      #pragma unroll 8
      for(int i=0;i<128;i++) s += sA[sg + i*8]*wq[sg + i*8];
      s += __shfl_xor(s,1); s += __shfl_xor(s,2); s += __shfl_xor(s,4);
      if (sg==0) sq[ml] = s;
    }
    if (tau>0 && tid>=256 && tid<416){
      int t2 = tid-256;
      int nl = t2>>3, sg = t2&7, nm = q4*20+nl;
      const float* wo = a.Wout + (size_t)nm*1536;
      float s=0.f;
      #pragma unroll 8
      for(int i=0;i<192;i++) s += sA[1024 + sg + i*8]*wo[sg + i*8];
      s += __shfl_xor(s,1); s += __shfl_xor(s,2); s += __shfl_xor(s,4);
      if (sg==0) a.outp[(size_t)b4*32000 + nm*400 + (tau-1)] = s + a.bout[nm];
    }
    __syncthreads();
    if (tau<400 && tid<256){
      for(int i=tid;i<1024;i+=256) sA[i] = a.Wloc[(q4*32 + (i>>5))*32 + (i&31)];
    }
    if (tid<32) sv[tid] = a.v_att[q4*32+tid];
    __syncthreads();
    if (tau<400 && tid<256){
      int t = tid;
      float lc[32];
      const float* lb = a.locT + (size_t)b4*8192 + t;
      #pragma unroll
      for(int f=0;f<32;f++) lc[f] = lb[f*256];
      const float* kb = a.keyp + ((size_t)b4*256 + t)*128 + q4*32;
      float acc=0.f;
      for(int mm=0;mm<32;mm++){
        float lf=0.f;
        #pragma unroll
        for(int f=0;f<32;f++) lf += lc[f]*sA[mm*32+f];
        acc += tanh_(sq[mm] + kb[mm] + lf)*sv[mm];
      }
      a.eP[b4*1024 + t*4 + q4] = acc;
    }
    if (tau==400) break;
    gbar(a.bar, bt);
    // ================= Phase C =================
    {
      float e=0.f, pe=0.f, mx=0.f;
      if (tid<256){
        const f32x4 ev = *(const f32x4*)(a.eP + b4*1024 + tid*4);
        e = ev[0]+ev[1]+ev[2]+ev[3];
        if (!mv) e = -1e9f;
        mx = e;
        #pragma unroll
        for(int off=1;off<64;off<<=1) mx = fmaxf(mx, __shfl_xor(mx,off));
        if (lan==0) red[wav] = mx;
      }
      __syncthreads();
      if (tid<256){
        mx = fmaxf(fmaxf(red[0],red[1]), fmaxf(red[2],red[3]));
        pe = __expf(e-mx);
        float sm = pe;
        #pragma unroll
        for(int off=1;off<64;off<<=1) sm += __shfl_xor(sm,off);
        if (lan==0) red[4+wav] = sm;
      }
      __syncthreads();
      if (tid<256){
        float sm = red[4]+red[5]+red[6]+red[7];
        float awt = pe/sm;
        if (q4==0){
          a.aw[b4*256+tid] = awt;
          a.awc[b4*256+tid] += awt;
          a.wout[(size_t)b4*102400 + (size_t)tid*400 + tau] = awt;
        }
        sA[tid] = awt;
      }
      __syncthreads();
      {
        int fl = tid&127, th = tid>>7;   // th in 0..3, 64 rows each
        const float* xp = a.xin + ((size_t)(b4*256 + th*64))*512 + q4*128 + fl;
        float s=0.f;
        for(int i=0;i<64;i++) s += sA[th*64+i]*xp[(size_t)i*512];
        sA[256+tid] = s;
      }
      __syncthreads();
      if (tid<128){
        float v = sA[256+tid] + sA[384+tid] + sA[512+tid] + sA[640+tid];
        int idx = b4*512 + q4*128 + tid;
        a.ctxf[idx] = v;
        a.ctxh[idx] = f2b(v);
      }
    }
    gbar(a.bar, bt);
  }
}

extern "C" void kernel_launch(void* const* d_in, const int* in_sizes, int n_in,
                              void* d_out, int out_size, void* d_ws, size_t ws_size,
                              hipStream_t stream){
  (void)in_sizes; (void)n_in; (void)out_size; (void)ws_size;
  const float* xin   = (const float*)d_in[0];
  const float* target= (const float*)d_in[2];
  const float* Wpre1 = (const float*)d_in[3];
  const float* bpre1 = (const float*)d_in[4];
  const float* Wpre2 = (const float*)d_in[5];
  const float* bpre2 = (const float*)d_in[6];
  const float* Wq    = (const float*)d_in[7];
  const float* Wk    = (const float*)d_in[8];
  const float* loc_conv = (const float*)d_in[9];
  const float* Wloc  = (const float*)d_in[10];
  const float* v_att = (const float*)d_in[11];
  const float* Wih1  = (const float*)d_in[12];
  const float* Whh1  = (const float*)d_in[13];
  const float* bih1  = (const float*)d_in[14];
  const float* bhh1  = (const float*)d_in[15];
  const float* Wih2  = (const float*)d_in[16];
  const float* Whh2  = (const float*)d_in[17];
  const float* bih2  = (const float*)d_in[18];
  const float* bhh2  = (const float*)d_in[19];
  const float* Wout  = (const float*)d_in[20];
  const float* boutp = (const float*)d_in[21];

  char* w = (char*)d_ws;
  auto carve=[&](size_t bytes)->void*{ void* r=(void*)w; w += (bytes+255)&~(size_t)255; return r; };
  // state region (zeroed every launch) — must stay first & contiguous
  unsigned short* h1h = (unsigned short*)carve((size_t)2*64*1024*2);
  unsigned short* h2h = (unsigned short*)carve((size_t)2*64*1024*2);
  unsigned short* ctxh= (unsigned short*)carve((size_t)64*512*2);
  float* h1f = (float*)carve((size_t)64*1024*4);
  float* h2f = (float*)carve((size_t)64*1024*4);
  float* ctxf= (float*)carve((size_t)64*512*4);
  float* c1  = (float*)carve((size_t)64*1024*4);
  float* c2  = (float*)carve((size_t)64*1024*4);
  float* aw  = (float*)carve((size_t)64*256*4);
  float* awc = (float*)carve((size_t)64*256*4);
  unsigned* bar = (unsigned*)carve(256);
  int* mflag = (int*)carve(256);
  size_t state_bytes = (size_t)(w - (char*)d_ws);
  float* eP   = (float*)carve((size_t)64*256*4*4);
  float* locT = (float*)carve((size_t)64*32*256*4);
  float* keyp = (float*)carve((size_t)64*256*128*4);
  unsigned short* xbh = (unsigned short*)carve((size_t)400*64*256*2);
  float* bsum1 = (float*)carve((size_t)4096*4);
  float* bsum2 = (float*)carve((size_t)4096*4);
  unsigned short* Wp1h = (unsigned short*)carve((size_t)256*56*512*2);
  unsigned short* Wp2h = (unsigned short*)carve((size_t)256*80*512*2);

  hipMemsetAsync(d_ws, 0, state_bytes, stream);
  maskdet_k<<<1, 256, 0, stream>>>((const unsigned*)d_in[1], mflag);
  prenet_k<<<400, 256, 0, stream>>>(target, Wpre1, bpre1, Wpre2, bpre2, xbh);
  keyproj_k<<<1024, 128, 0, stream>>>(xin, Wk, keyp);
  prep_k<<<16, 256, 0, stream>>>(bih1,bhh1,bih2,bhh2,bsum1,bsum2);
  perm_k<<<2048, 256, 0, stream>>>(Wih1,Whh1,Wih2,Whh2,Wp1h,Wp2h);

  SArgs a;
  a.xin=xin; a.loc_conv=loc_conv; a.Wloc=Wloc; a.v_att=v_att; a.bout=boutp;
  a.Wq=Wq; a.Wout=Wout;
  a.keyp=keyp; a.xbh=xbh;
  a.Wp1h=Wp1h; a.Wp2h=Wp2h;
  a.bsum1=bsum1; a.bsum2=bsum2;
  a.mask8=(const unsigned char*)d_in[1]; a.mask32=(const int*)d_in[1]; a.mflag=mflag;
  a.h1h=h1h; a.h1f=h1f;
  a.h2h=h2h; a.h2f=h2f;
  a.ctxh=ctxh; a.ctxf=ctxf;
  a.c1=c1; a.c2=c2;
  a.aw=aw; a.awc=awc; a.eP=eP; a.locT=locT; a.bar=bar;
  a.outp=(float*)d_out; a.wout=(float*)d_out + (size_t)64*80*400;

  scan_kernel<<<dim3(NB), dim3(NT), 0, stream>>>(a);
}

// Round 15
// 70846.069 us; speedup vs baseline: 4.7744x; 1.0163x over previous
//
#include <hip/hip_runtime.h>

#define NB 256
#define NT 512
// dynamic LDS layout (bytes):
//   [0,      57344)  Wp1 slice (28672 bf16)
//   [57344, 139264)  Wp2 slice (40960 bf16)
//   [139264,143616)  gsc1 (64*17 f32)
//   [143616,147968)  gsc2 (64*17 f32)
//   [147968,158208)  sA (2560 f32)
//   [158208,158336)  sq (32 f32)
//   [158336,158464)  sv (32 f32)
//   [158464,158496)  red (8 f32)
#define DYNB 158496

typedef __attribute__((ext_vector_type(8))) short short8;
typedef __attribute__((ext_vector_type(4))) float f32x4;

__device__ __forceinline__ float b2f(unsigned short s){ return __uint_as_float(((unsigned)s)<<16); }
__device__ __forceinline__ unsigned short f2b(float f){
  unsigned u = __float_as_uint(f);
  return (unsigned short)((u + 0x7FFFu + ((u>>16)&1u))>>16);
}
__device__ __forceinline__ float sigm(float x){ return 1.0f/(1.0f+__expf(-x)); }
__device__ __forceinline__ float tanh_(float x){ float e=__expf(-2.0f*x); return (1.0f-e)/(1.0f+e); }
__device__ __forceinline__ f32x4 mfma16(short8 a, short8 b, f32x4 c){
  return __builtin_amdgcn_mfma_f32_16x16x32_bf16(a,b,c,0,0,0);
}

__device__ __forceinline__ void gbar(unsigned* bar, unsigned& target){
  __syncthreads();
  if (threadIdx.x==0){
    target += NB;
    __threadfence();
    atomicAdd(bar, 1u);
    while (__hip_atomic_load(bar, __ATOMIC_ACQUIRE, __HIP_MEMORY_SCOPE_AGENT) < target){
      __builtin_amdgcn_s_sleep(1);
    }
    __threadfence();
  }
  __syncthreads();
}

// ---------------- precompute kernels ----------------

__global__ void maskdet_k(const unsigned* __restrict__ m32, int* __restrict__ flag){
  __shared__ int ok;
  if (threadIdx.x==0) ok = 1;
  __syncthreads();
  for (int i=threadIdx.x; i<4096; i+=256){
    if (m32[i] > 1u) ok = 0;
  }
  __syncthreads();
  if (threadIdx.x==0) *flag = ok;
}

__global__ void prenet_k(const float* __restrict__ target, const float* __restrict__ W1, const float* __restrict__ b1,
                         const float* __restrict__ W2, const float* __restrict__ b2,
                         unsigned short* __restrict__ xbh){
  int t = blockIdx.x;
  int tid = threadIdx.x;
  __shared__ float stgt[64][80];
  __shared__ float smid[64][256];
  for(int i=tid;i<64*80;i+=256){
    int b=i/80, c=i%80;
    stgt[b][c] = (t==0)?0.f : target[((size_t)b*80+c)*400 + (t-1)];
  }
  __syncthreads();
  {
    float w1r[80];
    #pragma unroll
    for(int c=0;c<80;c++) w1r[c] = W1[tid*80+c];
    float bb1 = b1[tid];
    for(int b0=0;b0<64;b0+=16){
      float acc[16];
      #pragma unroll
      for(int i=0;i<16;i++) acc[i]=0.f;
      for(int c=0;c<80;c++){
        float wv=w1r[c];
        #pragma unroll
        for(int i=0;i<16;i++) acc[i] += wv*stgt[b0+i][c];
      }
      #pragma unroll
      for(int i=0;i<16;i++) smid[b0+i][tid] = fmaxf(acc[i]+bb1, 0.f);
    }
  }
  __syncthreads();
  {
    float bb2 = b2[tid];
    for(int b0=0;b0<64;b0+=16){
      float acc[16];
      #pragma unroll
      for(int i=0;i<16;i++) acc[i]=0.f;
      for(int c=0;c<256;c++){
        float wv=W2[tid*256+c];
        #pragma unroll
        for(int i=0;i<16;i++) acc[i] += wv*smid[b0+i][c];
      }
      #pragma unroll
      for(int i=0;i<16;i++){
        float v = fmaxf(acc[i]+bb2,0.f);
        xbh[((size_t)t*64 + b0+i)*256 + tid] = f2b(v);
      }
    }
  }
}

__global__ void keyproj_k(const float* __restrict__ xin, const float* __restrict__ Wk, float* __restrict__ keyp){
  int b = blockIdx.x>>4; int t0=(blockIdx.x&15)*16; int m=threadIdx.x; // 128 threads
  __shared__ float sx[16][512];
  for(int i=m;i<16*512;i+=128){ int tt=i>>9, f=i&511; sx[tt][f]=xin[((size_t)b*256+t0+tt)*512+f]; }
  __syncthreads();
  float s[16];
  #pragma unroll
  for(int i=0;i<16;i++) s[i]=0.f;
  for(int f=0;f<512;f++){
    float wv = Wk[m*512+f];
    #pragma unroll
    for(int i=0;i<16;i++) s[i]+=sx[i][f]*wv;
  }
  #pragma unroll
  for(int i=0;i<16;i++) keyp[((size_t)b*256+t0+i)*128+m]=s[i];
}

__global__ void prep_k(const float* bih1,const float* bhh1,const float* bih2,const float* bhh2,
                       float* bsum1,float* bsum2){
  int i0 = blockIdx.x*blockDim.x + threadIdx.x;
  int n = gridDim.x*blockDim.x;
  for(int k=i0;k<4096;k+=n){ bsum1[k]=bih1[k]+bhh1[k]; bsum2[k]=bih2[k]+bhh2[k]; }
}

__global__ void perm_k(const float* __restrict__ Wih1, const float* __restrict__ Whh1,
                       const float* __restrict__ Wih2, const float* __restrict__ Whh2,
                       unsigned short* __restrict__ Wp1h, unsigned short* __restrict__ Wp2h){
  size_t i0 = (size_t)blockIdx.x*blockDim.x + threadIdx.x;
  size_t n  = (size_t)gridDim.x*blockDim.x;
  const size_t N1 = (size_t)256*56*512;
  for(size_t idx=i0; idx<N1; idx+=n){
    int beta = (int)(idx/28672);
    int r = (int)(idx%28672);
    int kt = r/512;
    int l  = (r>>3)&63;
    int i8 = r&7;
    int c = l&15, cci = l>>4;
    int k = kt*32 + cci*8 + i8;
    int rowp = (c>>2)*1024 + beta*4 + (c&3);
    float v = (k<768)? Wih1[(size_t)rowp*768 + k] : Whh1[(size_t)rowp*1024 + (k-768)];
    Wp1h[idx] = f2b(v);
  }
  const size_t N2 = (size_t)256*80*512;
  for(size_t idx=i0; idx<N2; idx+=n){
    int beta = (int)(idx/40960);
    int r = (int)(idx%40960);
    int kt = r/512;
    int l  = (r>>3)&63;
    int i8 = r&7;
    int c = l&15, cci = l>>4;
    int k = kt*32 + cci*8 + i8;
    int rowp = (c>>2)*1024 + beta*4 + (c&3);
    float v = (k<1536)? Wih2[(size_t)rowp*1536 + k] : Whh2[(size_t)rowp*1024 + (k-1536)];
    Wp2h[idx] = f2b(v);
  }
}

// ---------------- the scan (persistent; weights LDS-resident) ----------------

struct SArgs {
  const float* xin; const float* loc_conv; const float* Wloc; const float* v_att; const float* bout;
  const float* Wq; const float* Wout;
  const float* keyp;
  const unsigned short* xbh;
  const unsigned short* Wp1h; const unsigned short* Wp2h;
  const float* bsum1; const float* bsum2;
  const unsigned char* mask8; const int* mask32; const int* mflag;
  unsigned short* h1h; float* h1f;
  unsigned short* h2h; float* h2f;
  unsigned short* ctxh; float* ctxf;
  float* c1; float* c2;
  float* aw; float* awc; float* eP; float* locT;
  unsigned* bar;
  float* outp; float* wout;
};

__global__ void __launch_bounds__(NT) scan_kernel(SArgs a){
  extern __shared__ char dynsm[];
  unsigned short* Lw1 = (unsigned short*)dynsm;             // 28672
  unsigned short* Lw2 = (unsigned short*)(dynsm + 57344);   // 40960
  float* gsc1 = (float*)(dynsm + 139264);                   // [64][17]
  float* gsc2 = (float*)(dynsm + 143616);                   // [64][17]
  float* sA   = (float*)(dynsm + 147968);                   // [2560]
  float* sq   = (float*)(dynsm + 158208);                   // [32]
  float* sv   = (float*)(dynsm + 158336);                   // [32]
  float* red  = (float*)(dynsm + 158464);                   // [8]

  const int beta = blockIdx.x;
  const int tid = threadIdx.x;
  const int wav = tid>>6;
  const int lan = tid&63;

  const int cc  = lan>>4;
  const int b4  = beta>>2;
  const int q4  = beta&3;
  unsigned bt = 0;

  // one-time: stage this block's weight slices into LDS
  {
    const short8* g1 = (const short8*)(a.Wp1h + (size_t)beta*28672);
    short8* l1 = (short8*)Lw1;
    for (int i=tid; i<3584; i+=NT) l1[i] = g1[i];
    const short8* g2 = (const short8*)(a.Wp2h + (size_t)beta*40960);
    short8* l2 = (short8*)Lw2;
    for (int i=tid; i<5120; i+=NT) l2[i] = g2[i];
  }

  bool mv = false;
  if (tid<256) mv = (a.mflag[0] ? (a.mask32[b4*256+tid] != 0) : (a.mask8[b4*256+tid] != 0));
  __syncthreads();

  for (int tau=0; tau<=400; ++tau){
    const int p = tau&1;
    // ================= Phase A: LSTM1 (waves 0-3) ∥ LSTM2 (waves 4-7) =================
    if (tau<400 && wav<4){
      const int row = wav*16 + (lan&15);
      f32x4 A0={0.f,0.f,0.f,0.f};
      const unsigned short* wh = Lw1 + lan*8;
      {
        const unsigned short* xh = a.xbh + ((size_t)tau*64 + row)*256 + cc*8;
        #pragma unroll
        for(int kt=0;kt<8;kt++)
          A0=mfma16(*(const short8*)(xh+kt*32), *(const short8*)(wh+kt*512), A0);
      }
      {
        const unsigned short* xh = a.ctxh + row*512 + cc*8;
        #pragma unroll 8
        for(int kt=8;kt<24;kt++)
          A0=mfma16(*(const short8*)(xh+(kt-8)*32), *(const short8*)(wh+kt*512), A0);
      }
      {
        const unsigned short* xh = a.h1h + (size_t)(p^1)*65536 + row*1024 + cc*8;
        #pragma unroll 8
        for(int kt=24;kt<56;kt++)
          A0=mfma16(*(const short8*)(xh+(kt-24)*32), *(const short8*)(wh+kt*512), A0);
      }
      #pragma unroll
      for(int r=0;r<4;r++) gsc1[(wav*16 + cc*4 + r)*17 + (lan&15)] = A0[r];
    }
    if (tau>0 && wav>=4){
      const int wv2 = wav-4;
      const int row = wv2*16 + (lan&15);
      f32x4 A0={0.f,0.f,0.f,0.f};
      const unsigned short* wh = Lw2 + lan*8;
      {
        const unsigned short* xh = a.h1h + (size_t)(p^1)*65536 + row*1024 + cc*8;
        #pragma unroll 8
        for(int kt=0;kt<32;kt++)
          A0=mfma16(*(const short8*)(xh+kt*32), *(const short8*)(wh+kt*512), A0);
      }
      {
        const unsigned short* xh = a.ctxh + row*512 + cc*8;
        #pragma unroll 8
        for(int kt=32;kt<48;kt++)
          A0=mfma16(*(const short8*)(xh+(kt-32)*32), *(const short8*)(wh+kt*512), A0);
      }
      {
        const unsigned short* xh = a.h2h + (size_t)p*65536 + row*1024 + cc*8;
        #pragma unroll 8
        for(int kt=48;kt<80;kt++)
          A0=mfma16(*(const short8*)(xh+(kt-48)*32), *(const short8*)(wh+kt*512), A0);
      }
      #pragma unroll
      for(int r=0;r<4;r++) gsc2[(wv2*16 + cc*4 + r)*17 + (lan&15)] = A0[r];
    }
    __syncthreads();
    if (tau<400 && tid<256){
      int m = tid>>2, j = tid&3, u = beta*4+j;
      float gi = gsc1[m*17+0+j]  + a.bsum1[0*1024+u];
      float gf = gsc1[m*17+4+j]  + a.bsum1[1*1024+u];
      float gg = gsc1[m*17+8+j]  + a.bsum1[2*1024+u];
      float go = gsc1[m*17+12+j] + a.bsum1[3*1024+u];
      float cp = a.c1[m*1024+u];
      float cn = sigm(gf)*cp + sigm(gi)*tanh_(gg);
      a.c1[m*1024+u] = cn;
      float hn = sigm(go)*tanh_(cn);
      a.h1f[m*1024+u] = hn;
      a.h1h[(size_t)p*65536 + m*1024 + u] = f2b(hn);
    }
    if (tau>0 && tid>=256){
      int t2 = tid-256;
      int m = t2>>2, j = t2&3, u = beta*4+j;
      float gi = gsc2[m*17+0+j]  + a.bsum2[0*1024+u];
      float gf = gsc2[m*17+4+j]  + a.bsum2[1*1024+u];
      float gg = gsc2[m*17+8+j]  + a.bsum2[2*1024+u];
      float go = gsc2[m*17+12+j] + a.bsum2[3*1024+u];
      float cp = a.c2[m*1024+u];
      float cn = sigm(gf)*cp + sigm(gi)*tanh_(gg);
      a.c2[m*1024+u] = cn;
      float hn = sigm(go)*tanh_(cn);
      a.h2f[m*1024+u] = hn;
      a.h2h[(size_t)(p^1)*65536 + m*1024 + u] = f2b(hn);
    }
    if (tau<400){
      for(int i=tid;i<256;i+=NT){ sA[i] = a.aw[b4*256+i]; sA[256+i] = a.awc[b4*256+i]; }
      for(int i=tid;i<1984;i+=NT) sA[512+i] = a.loc_conv[i];
    }
    __syncthreads();
    if (tau<400){
      const int t0 = q4*64;
      #pragma unroll
      for(int jj=0;jj<4;jj++){
        int o = tid*4+jj;
        int f = o>>6, tl = o&63, t = t0+tl;
        float s = 0.f;
        #pragma unroll
        for(int c=0;c<2;c++){
          const float* kw = &sA[512 + (f*2+c)*31];
          const float* wv = &sA[c*256];
          for(int k=0;k<31;k++){
            int tt = t + k - 15;
            if (tt>=0 && tt<256) s += wv[tt]*kw[k];
          }
        }
        a.locT[(size_t)b4*8192 + f*256 + t] = s;
      }
    }
    gbar(a.bar, bt);
    // ================= Phase B: q/e path (tid<256) ∥ out-proj (tid 256-415) =================
    if (tau<400 && tid<256){
      for(int i=tid;i<1024;i+=256) sA[i] = a.h1f[b4*1024 + i];
    }
    if (tau>0 && tid>=256){
      int t2 = tid-256;
      for(int i=t2;i<1024;i+=256) sA[1024+i] = a.h2f[b4*1024 + i];
      for(int i=t2;i<512;i+=256)  sA[2048+i] = a.ctxf[b4*512 + i];
    }
    __syncthreads();
    if (tau<400 && tid<256){
      int ml = tid>>3, sg = tid&7;
      const float* wq = a.Wq + (size_t)(q4*32+ml)*1024;
      float s=0.f;
      #pragma unroll 8
      for(int i=0;i<128;i++) s += sA[sg + i*8]*wq[sg + i*8];
      s += __shfl_xor(s,1); s += __shfl_xor(s,2); s += __shfl_xor(s,4);
      if (sg==0) sq[ml] = s;
    }
    if (tau>0 && tid>=256 && tid<416){
      int t2 = tid-256;
      int nl = t2>>3, sg = t2&7, nm = q4*20+nl;
      const float* wo = a.Wout + (size_t)nm*1536;
      float s=0.f;
      #pragma unroll 8
      for(int i=0;i<192;i++) s += sA[1024 + sg + i*8]*wo[sg + i*8];
      s += __shfl_xor(s,1); s += __shfl_xor(s,2); s += __shfl_xor(s,4);
      if (sg==0) a.outp[(size_t)b4*32000 + nm*400 + (tau-1)] = s + a.bout[nm];
    }
    __syncthreads();
    if (tau<400 && tid<256){
      for(int i=tid;i<1024;i+=256) sA[i] = a.Wloc[(q4*32 + (i>>5))*32 + (i&31)];
    }
    if (tid<32) sv[tid] = a.v_att[q4*32+tid];
    __syncthreads();
    if (tau<400 && tid<256){
      int t = tid;
      float lc[32];
      const float* lb = a.locT + (size_t)b4*8192 + t;
      #pragma unroll
      for(int f=0;f<32;f++) lc[f] = lb[f*256];
      const float* kb = a.keyp + ((size_t)b4*256 + t)*128 + q4*32;
      float acc=0.f;
      for(int mm=0;mm<32;mm++){
        float lf=0.f;
        #pragma unroll
        for(int f=0;f<32;f++) lf += lc[f]*sA[mm*32+f];
        acc += tanh_(sq[mm] + kb[mm] + lf)*sv[mm];
      }
      a.eP[b4*1024 + t*4 + q4] = acc;
    }
    if (tau==400) break;
    gbar(a.bar, bt);
    // ================= Phase C =================
    {
      float e=0.f, pe=0.f, mx=0.f;
      if (tid<256){
        const f32x4 ev = *(const f32x4*)(a.eP + b4*1024 + tid*4);
        e = ev[0]+ev[1]+ev[2]+ev[3];
        if (!mv) e = -1e9f;
        mx = e;
        #pragma unroll
        for(int off=1;off<64;off<<=1) mx = fmaxf(mx, __shfl_xor(mx,off));
        if (lan==0) red[wav] = mx;
      }
      __syncthreads();
      if (tid<256){
        mx = fmaxf(fmaxf(red[0],red[1]), fmaxf(red[2],red[3]));
        pe = __expf(e-mx);
        float sm = pe;
        #pragma unroll
        for(int off=1;off<64;off<<=1) sm += __shfl_xor(sm,off);
        if (lan==0) red[4+wav] = sm;
      }
      __syncthreads();
      if (tid<256){
        float sm = red[4]+red[5]+red[6]+red[7];
        float awt = pe/sm;
        if (q4==0){
          a.aw[b4*256+tid] = awt;
          a.awc[b4*256+tid] += awt;
          a.wout[(size_t)b4*102400 + (size_t)tid*400 + tau] = awt;
        }
        sA[tid] = awt;
      }
      __syncthreads();
      {
        int fl = tid&127, th = tid>>7;
        const float* xp = a.xin + ((size_t)(b4*256 + th*64))*512 + q4*128 + fl;
        float s=0.f;
        for(int i=0;i<64;i++) s += sA[th*64+i]*xp[(size_t)i*512];
        sA[256+tid] = s;
      }
      __syncthreads();
      if (tid<128){
        float v = sA[256+tid] + sA[384+tid] + sA[512+tid] + sA[640+tid];
        int idx = b4*512 + q4*128 + tid;
        a.ctxf[idx] = v;
        a.ctxh[idx] = f2b(v);
      }
    }
    gbar(a.bar, bt);
  }
}

extern "C" void kernel_launch(void* const* d_in, const int* in_sizes, int n_in,
                              void* d_out, int out_size, void* d_ws, size_t ws_size,
                              hipStream_t stream){
  (void)in_sizes; (void)n_in; (void)out_size; (void)ws_size;
  const float* xin   = (const float*)d_in[0];
  const float* target= (const float*)d_in[2];
  const float* Wpre1 = (const float*)d_in[3];
  const float* bpre1 = (const float*)d_in[4];
  const float* Wpre2 = (const float*)d_in[5];
  const float* bpre2 = (const float*)d_in[6];
  const float* Wq    = (const float*)d_in[7];
  const float* Wk    = (const float*)d_in[8];
  const float* loc_conv = (const float*)d_in[9];
  const float* Wloc  = (const float*)d_in[10];
  const float* v_att = (const float*)d_in[11];
  const float* Wih1  = (const float*)d_in[12];
  const float* Whh1  = (const float*)d_in[13];
  const float* bih1  = (const float*)d_in[14];
  const float* bhh1  = (const float*)d_in[15];
  const float* Wih2  = (const float*)d_in[16];
  const float* Whh2  = (const float*)d_in[17];
  const float* bih2  = (const float*)d_in[18];
  const float* bhh2  = (const float*)d_in[19];
  const float* Wout  = (const float*)d_in[20];
  const float* boutp = (const float*)d_in[21];

  char* w = (char*)d_ws;
  auto carve=[&](size_t bytes)->void*{ void* r=(void*)w; w += (bytes+255)&~(size_t)255; return r; };
  // state region (zeroed every launch) — must stay first & contiguous
  unsigned short* h1h = (unsigned short*)carve((size_t)2*64*1024*2);
  unsigned short* h2h = (unsigned short*)carve((size_t)2*64*1024*2);
  unsigned short* ctxh= (unsigned short*)carve((size_t)64*512*2);
  float* h1f = (float*)carve((size_t)64*1024*4);
  float* h2f = (float*)carve((size_t)64*1024*4);
  float* ctxf= (float*)carve((size_t)64*512*4);
  float* c1  = (float*)carve((size_t)64*1024*4);
  float* c2  = (float*)carve((size_t)64*1024*4);
  float* aw  = (float*)carve((size_t)64*256*4);
  float* awc = (float*)carve((size_t)64*256*4);
  unsigned* bar = (unsigned*)carve(256);
  int* mflag = (int*)carve(256);
  size_t state_bytes = (size_t)(w - (char*)d_ws);
  float* eP   = (float*)carve((size_t)64*256*4*4);
  float* locT = (float*)carve((size_t)64*32*256*4);
  float* keyp = (float*)carve((size_t)64*256*128*4);
  unsigned short* xbh = (unsigned short*)carve((size_t)400*64*256*2);
  float* bsum1 = (float*)carve((size_t)4096*4);
  float* bsum2 = (float*)carve((size_t)4096*4);
  unsigned short* Wp1h = (unsigned short*)carve((size_t)256*56*512*2);
  unsigned short* Wp2h = (unsigned short*)carve((size_t)256*80*512*2);

  hipMemsetAsync(d_ws, 0, state_bytes, stream);
  maskdet_k<<<1, 256, 0, stream>>>((const unsigned*)d_in[1], mflag);
  prenet_k<<<400, 256, 0, stream>>>(target, Wpre1, bpre1, Wpre2, bpre2, xbh);
  keyproj_k<<<1024, 128, 0, stream>>>(xin, Wk, keyp);
  prep_k<<<16, 256, 0, stream>>>(bih1,bhh1,bih2,bhh2,bsum1,bsum2);
  perm_k<<<2048, 256, 0, stream>>>(Wih1,Whh1,Wih2,Whh2,Wp1h,Wp2h);

  SArgs a;
  a.xin=xin; a.loc_conv=loc_conv; a.Wloc=Wloc; a.v_att=v_att; a.bout=boutp;
  a.Wq=Wq; a.Wout=Wout;
  a.keyp=keyp; a.xbh=xbh;
  a.Wp1h=Wp1h; a.Wp2h=Wp2h;
  a.bsum1=bsum1; a.bsum2=bsum2;
  a.mask8=(const unsigned char*)d_in[1]; a.mask32=(const int*)d_in[1]; a.mflag=mflag;
  a.h1h=h1h; a.h1f=h1f;
  a.h2h=h2h; a.h2f=h2f;
  a.ctxh=ctxh; a.ctxf=ctxf;
  a.c1=c1; a.c2=c2;
  a.aw=aw; a.awc=awc; a.eP=eP; a.locT=locT; a.bar=bar;
  a.outp=(float*)d_out; a.wout=(float*)d_out + (size_t)64*80*400;

  hipFuncSetAttribute((const void*)scan_kernel, hipFuncAttributeMaxDynamicSharedMemorySize, DYNB);
  scan_kernel<<<dim3(NB), dim3(NT), DYNB, stream>>>(a);
}

// Round 16
// 68446.246 us; speedup vs baseline: 4.9418x; 1.0351x over previous
//
#include <hip/hip_runtime.h>

#define NB 256
#define NT 512
#define DYNB 158496
#define SCOPE __HIP_MEMORY_SCOPE_AGENT

typedef __attribute__((ext_vector_type(8))) short short8;
typedef __attribute__((ext_vector_type(4))) float f32x4;

__device__ __forceinline__ float b2f(unsigned short s){ return __uint_as_float(((unsigned)s)<<16); }
__device__ __forceinline__ unsigned short f2b(float f){
  unsigned u = __float_as_uint(f);
  return (unsigned short)((u + 0x7FFFu + ((u>>16)&1u))>>16);
}
__device__ __forceinline__ float sigm(float x){ return 1.0f/(1.0f+__expf(-x)); }
__device__ __forceinline__ float tanh_(float x){ float e=__expf(-2.0f*x); return (1.0f-e)/(1.0f+e); }
__device__ __forceinline__ f32x4 mfma16(short8 a, short8 b, f32x4 c){
  return __builtin_amdgcn_mfma_f32_16x16x32_bf16(a,b,c,0,0,0);
}

// device-coherent (sc1) access helpers: bypass incoherent L1/L2, no cache
// invalidation needed anywhere. Compiler tracks vmcnt for these.
__device__ __forceinline__ float ldf(const float* p){
  return __hip_atomic_load((float*)p, __ATOMIC_RELAXED, SCOPE);
}
__device__ __forceinline__ void stf(float* p, float v){
  __hip_atomic_store(p, v, __ATOMIC_RELAXED, SCOPE);
}
__device__ __forceinline__ void sth(unsigned short* p, unsigned short v){
  __hip_atomic_store(p, v, __ATOMIC_RELAXED, SCOPE);
}
__device__ __forceinline__ short8 ld8h(const unsigned short* p){
  const unsigned* q = (const unsigned*)p;
  union{ unsigned u[4]; short8 s; } r;
  r.u[0]=__hip_atomic_load((unsigned*)(q+0), __ATOMIC_RELAXED, SCOPE);
  r.u[1]=__hip_atomic_load((unsigned*)(q+1), __ATOMIC_RELAXED, SCOPE);
  r.u[2]=__hip_atomic_load((unsigned*)(q+2), __ATOMIC_RELAXED, SCOPE);
  r.u[3]=__hip_atomic_load((unsigned*)(q+3), __ATOMIC_RELAXED, SCOPE);
  return r.s;
}

// grid barrier: no threadfence (no L2 invalidate). __syncthreads drains each
// wave's outstanding (write-through) stores; exchange data is sc1-coherent.
__device__ __forceinline__ void gbar(unsigned* bar, unsigned& target){
  __syncthreads();
  if (threadIdx.x==0){
    target += NB;
    asm volatile("s_waitcnt vmcnt(0)" ::: "memory");
    __hip_atomic_fetch_add(bar, 1u, __ATOMIC_RELAXED, SCOPE);
    while (__hip_atomic_load(bar, __ATOMIC_RELAXED, SCOPE) < target){
      __builtin_amdgcn_s_sleep(1);
    }
  }
  __syncthreads();
}

// ---------------- precompute kernels (unchanged) ----------------

__global__ void maskdet_k(const unsigned* __restrict__ m32, int* __restrict__ flag){
  __shared__ int ok;
  if (threadIdx.x==0) ok = 1;
  __syncthreads();
  for (int i=threadIdx.x; i<4096; i+=256){
    if (m32[i] > 1u) ok = 0;
  }
  __syncthreads();
  if (threadIdx.x==0) *flag = ok;
}

__global__ void prenet_k(const float* __restrict__ target, const float* __restrict__ W1, const float* __restrict__ b1,
                         const float* __restrict__ W2, const float* __restrict__ b2,
                         unsigned short* __restrict__ xbh){
  int t = blockIdx.x;
  int tid = threadIdx.x;
  __shared__ float stgt[64][80];
  __shared__ float smid[64][256];
  for(int i=tid;i<64*80;i+=256){
    int b=i/80, c=i%80;
    stgt[b][c] = (t==0)?0.f : target[((size_t)b*80+c)*400 + (t-1)];
  }
  __syncthreads();
  {
    float w1r[80];
    #pragma unroll
    for(int c=0;c<80;c++) w1r[c] = W1[tid*80+c];
    float bb1 = b1[tid];
    for(int b0=0;b0<64;b0+=16){
      float acc[16];
      #pragma unroll
      for(int i=0;i<16;i++) acc[i]=0.f;
      for(int c=0;c<80;c++){
        float wv=w1r[c];
        #pragma unroll
        for(int i=0;i<16;i++) acc[i] += wv*stgt[b0+i][c];
      }
      #pragma unroll
      for(int i=0;i<16;i++) smid[b0+i][tid] = fmaxf(acc[i]+bb1, 0.f);
    }
  }
  __syncthreads();
  {
    float bb2 = b2[tid];
    for(int b0=0;b0<64;b0+=16){
      float acc[16];
      #pragma unroll
      for(int i=0;i<16;i++) acc[i]=0.f;
      for(int c=0;c<256;c++){
        float wv=W2[tid*256+c];
        #pragma unroll
        for(int i=0;i<16;i++) acc[i] += wv*smid[b0+i][c];
      }
      #pragma unroll
      for(int i=0;i<16;i++){
        float v = fmaxf(acc[i]+bb2,0.f);
        xbh[((size_t)t*64 + b0+i)*256 + tid] = f2b(v);
      }
    }
  }
}

__global__ void keyproj_k(const float* __restrict__ xin, const float* __restrict__ Wk, float* __restrict__ keyp){
  int b = blockIdx.x>>4; int t0=(blockIdx.x&15)*16; int m=threadIdx.x; // 128 threads
  __shared__ float sx[16][512];
  for(int i=m;i<16*512;i+=128){ int tt=i>>9, f=i&511; sx[tt][f]=xin[((size_t)b*256+t0+tt)*512+f]; }
  __syncthreads();
  float s[16];
  #pragma unroll
  for(int i=0;i<16;i++) s[i]=0.f;
  for(int f=0;f<512;f++){
    float wv = Wk[m*512+f];
    #pragma unroll
    for(int i=0;i<16;i++) s[i]+=sx[i][f]*wv;
  }
  #pragma unroll
  for(int i=0;i<16;i++) keyp[((size_t)b*256+t0+i)*128+m]=s[i];
}

__global__ void prep_k(const float* bih1,const float* bhh1,const float* bih2,const float* bhh2,
                       float* bsum1,float* bsum2){
  int i0 = blockIdx.x*blockDim.x + threadIdx.x;
  int n = gridDim.x*blockDim.x;
  for(int k=i0;k<4096;k+=n){ bsum1[k]=bih1[k]+bhh1[k]; bsum2[k]=bih2[k]+bhh2[k]; }
}

__global__ void perm_k(const float* __restrict__ Wih1, const float* __restrict__ Whh1,
                       const float* __restrict__ Wih2, const float* __restrict__ Whh2,
                       unsigned short* __restrict__ Wp1h, unsigned short* __restrict__ Wp2h){
  size_t i0 = (size_t)blockIdx.x*blockDim.x + threadIdx.x;
  size_t n  = (size_t)gridDim.x*blockDim.x;
  const size_t N1 = (size_t)256*56*512;
  for(size_t idx=i0; idx<N1; idx+=n){
    int beta = (int)(idx/28672);
    int r = (int)(idx%28672);
    int kt = r/512;
    int l  = (r>>3)&63;
    int i8 = r&7;
    int c = l&15, cci = l>>4;
    int k = kt*32 + cci*8 + i8;
    int rowp = (c>>2)*1024 + beta*4 + (c&3);
    float v = (k<768)? Wih1[(size_t)rowp*768 + k] : Whh1[(size_t)rowp*1024 + (k-768)];
    Wp1h[idx] = f2b(v);
  }
  const size_t N2 = (size_t)256*80*512;
  for(size_t idx=i0; idx<N2; idx+=n){
    int beta = (int)(idx/40960);
    int r = (int)(idx%40960);
    int kt = r/512;
    int l  = (r>>3)&63;
    int i8 = r&7;
    int c = l&15, cci = l>>4;
    int k = kt*32 + cci*8 + i8;
    int rowp = (c>>2)*1024 + beta*4 + (c&3);
    float v = (k<1536)? Wih2[(size_t)rowp*1536 + k] : Whh2[(size_t)rowp*1024 + (k-1536)];
    Wp2h[idx] = f2b(v);
  }
}

// ---------------- the scan ----------------

struct SArgs {
  const float* xin; const float* loc_conv; const float* Wloc; const float* v_att; const float* bout;
  const float* Wq; const float* Wout;
  const float* keyp;
  const unsigned short* xbh;
  const unsigned short* Wp1h; const unsigned short* Wp2h;
  const float* bsum1; const float* bsum2;
  const unsigned char* mask8; const int* mask32; const int* mflag;
  unsigned short* h1h; float* h1f;
  unsigned short* h2h; float* h2f;
  unsigned short* ctxh; float* ctxf;
  float* c1; float* c2;
  float* aw; float* awc; float* eP; float* locT;
  unsigned* bar;
  float* outp; float* wout;
};

__global__ void __launch_bounds__(NT) scan_kernel(SArgs a){
  extern __shared__ char dynsm[];
  unsigned short* Lw1 = (unsigned short*)dynsm;             // 28672
  unsigned short* Lw2 = (unsigned short*)(dynsm + 57344);   // 40960
  float* gsc1 = (float*)(dynsm + 139264);                   // [64][17]
  float* gsc2 = (float*)(dynsm + 143616);                   // [64][17]
  float* sA   = (float*)(dynsm + 147968);                   // [2560]
  float* sq   = (float*)(dynsm + 158208);                   // [32]
  float* sv   = (float*)(dynsm + 158336);                   // [32]
  float* red  = (float*)(dynsm + 158464);                   // [8]

  const int beta = blockIdx.x;
  const int tid = threadIdx.x;
  const int wav = tid>>6;
  const int lan = tid&63;

  const int cc  = lan>>4;
  const int b4  = beta>>2;
  const int q4  = beta&3;
  unsigned bt = 0;

  // one-time: stage this block's weight slices into LDS
  {
    const short8* g1 = (const short8*)(a.Wp1h + (size_t)beta*28672);
    short8* l1 = (short8*)Lw1;
    for (int i=tid; i<3584; i+=NT) l1[i] = g1[i];
    const short8* g2 = (const short8*)(a.Wp2h + (size_t)beta*40960);
    short8* l2 = (short8*)Lw2;
    for (int i=tid; i<5120; i+=NT) l2[i] = g2[i];
  }

  bool mv = false;
  if (tid<256) mv = (a.mflag[0] ? (a.mask32[b4*256+tid] != 0) : (a.mask8[b4*256+tid] != 0));
  __syncthreads();

  for (int tau=0; tau<=400; ++tau){
    const int p = tau&1;
    // ================= Phase A: LSTM1 (waves 0-3) ∥ LSTM2 (waves 4-7) =================
    if (tau<400 && wav<4){
      const int row = wav*16 + (lan&15);
      f32x4 A0={0.f,0.f,0.f,0.f};
      const unsigned short* wh = Lw1 + lan*8;
      {
        const unsigned short* xh = a.xbh + ((size_t)tau*64 + row)*256 + cc*8;
        #pragma unroll
        for(int kt=0;kt<8;kt++)
          A0=mfma16(*(const short8*)(xh+kt*32), *(const short8*)(wh+kt*512), A0);
      }
      {
        const unsigned short* xh = a.ctxh + row*512 + cc*8;
        #pragma unroll 8
        for(int kt=8;kt<24;kt++)
          A0=mfma16(ld8h(xh+(kt-8)*32), *(const short8*)(wh+kt*512), A0);
      }
      {
        const unsigned short* xh = a.h1h + (size_t)(p^1)*65536 + row*1024 + cc*8;
        #pragma unroll 8
        for(int kt=24;kt<56;kt++)
          A0=mfma16(ld8h(xh+(kt-24)*32), *(const short8*)(wh+kt*512), A0);
      }
      #pragma unroll
      for(int r=0;r<4;r++) gsc1[(wav*16 + cc*4 + r)*17 + (lan&15)] = A0[r];
    }
    if (tau>0 && wav>=4){
      const int wv2 = wav-4;
      const int row = wv2*16 + (lan&15);
      f32x4 A0={0.f,0.f,0.f,0.f};
      const unsigned short* wh = Lw2 + lan*8;
      {
        const unsigned short* xh = a.h1h + (size_t)(p^1)*65536 + row*1024 + cc*8;
        #pragma unroll 8
        for(int kt=0;kt<32;kt++)
          A0=mfma16(ld8h(xh+kt*32), *(const short8*)(wh+kt*512), A0);
      }
      {
        const unsigned short* xh = a.ctxh + row*512 + cc*8;
        #pragma unroll 8
        for(int kt=32;kt<48;kt++)
          A0=mfma16(ld8h(xh+(kt-32)*32), *(const short8*)(wh+kt*512), A0);
      }
      {
        const unsigned short* xh = a.h2h + (size_t)p*65536 + row*1024 + cc*8;
        #pragma unroll 8
        for(int kt=48;kt<80;kt++)
          A0=mfma16(ld8h(xh+(kt-48)*32), *(const short8*)(wh+kt*512), A0);
      }
      #pragma unroll
      for(int r=0;r<4;r++) gsc2[(wv2*16 + cc*4 + r)*17 + (lan&15)] = A0[r];
    }
    __syncthreads();
    if (tau<400 && tid<256){
      int m = tid>>2, j = tid&3, u = beta*4+j;
      float gi = gsc1[m*17+0+j]  + a.bsum1[0*1024+u];
      float gf = gsc1[m*17+4+j]  + a.bsum1[1*1024+u];
      float gg = gsc1[m*17+8+j]  + a.bsum1[2*1024+u];
      float go = gsc1[m*17+12+j] + a.bsum1[3*1024+u];
      float cp = a.c1[m*1024+u];
      float cn = sigm(gf)*cp + sigm(gi)*tanh_(gg);
      a.c1[m*1024+u] = cn;
      float hn = sigm(go)*tanh_(cn);
      stf(a.h1f + m*1024+u, hn);
      sth(a.h1h + (size_t)p*65536 + m*1024 + u, f2b(hn));
    }
    if (tau>0 && tid>=256){
      int t2 = tid-256;
      int m = t2>>2, j = t2&3, u = beta*4+j;
      float gi = gsc2[m*17+0+j]  + a.bsum2[0*1024+u];
      float gf = gsc2[m*17+4+j]  + a.bsum2[1*1024+u];
      float gg = gsc2[m*17+8+j]  + a.bsum2[2*1024+u];
      float go = gsc2[m*17+12+j] + a.bsum2[3*1024+u];
      float cp = a.c2[m*1024+u];
      float cn = sigm(gf)*cp + sigm(gi)*tanh_(gg);
      a.c2[m*1024+u] = cn;
      float hn = sigm(go)*tanh_(cn);
      stf(a.h2f + m*1024+u, hn);
      sth(a.h2h + (size_t)(p^1)*65536 + m*1024 + u, f2b(hn));
    }
    if (tau<400){
      for(int i=tid;i<256;i+=NT){ sA[i] = ldf(a.aw + b4*256+i); sA[256+i] = ldf(a.awc + b4*256+i); }
      for(int i=tid;i<1984;i+=NT) sA[512+i] = a.loc_conv[i];
    }
    __syncthreads();
    if (tau<400){
      const int t0 = q4*64;
      #pragma unroll
      for(int jj=0;jj<4;jj++){
        int o = tid*4+jj;
        int f = o>>6, tl = o&63, t = t0+tl;
        float s = 0.f;
        #pragma unroll
        for(int c=0;c<2;c++){
          const float* kw = &sA[512 + (f*2+c)*31];
          const float* wv = &sA[c*256];
          for(int k=0;k<31;k++){
            int tt = t + k - 15;
            if (tt>=0 && tt<256) s += wv[tt]*kw[k];
          }
        }
        stf(a.locT + (size_t)b4*8192 + f*256 + t, s);
      }
    }
    gbar(a.bar, bt);
    // ================= Phase B: q/e path (tid<256) ∥ out-proj (tid 256-415) =================
    if (tau<400 && tid<256){
      for(int i=tid;i<1024;i+=256) sA[i] = ldf(a.h1f + b4*1024 + i);
    }
    if (tau>0 && tid>=256){
      int t2 = tid-256;
      for(int i=t2;i<1024;i+=256) sA[1024+i] = ldf(a.h2f + b4*1024 + i);
      for(int i=t2;i<512;i+=256)  sA[2048+i] = ldf(a.ctxf + b4*512 + i);
    }
    __syncthreads();
    if (tau<400 && tid<256){
      int ml = tid>>3, sg = tid&7;
      const float* wq = a.Wq + (size_t)(q4*32+ml)*1024;
      float s=0.f;
      #pragma unroll 8
      for(int i=0;i<128;i++) s += sA[sg + i*8]*wq[sg + i*8];
      s += __shfl_xor(s,1); s += __shfl_xor(s,2); s += __shfl_xor(s,4);
      if (sg==0) sq[ml] = s;
    }
    if (tau>0 && tid>=256 && tid<416){
      int t2 = tid-256;
      int nl = t2>>3, sg = t2&7, nm = q4*20+nl;
      const float* wo = a.Wout + (size_t)nm*1536;
      float s=0.f;
      #pragma unroll 8
      for(int i=0;i<192;i++) s += sA[1024 + sg + i*8]*wo[sg + i*8];
      s += __shfl_xor(s,1); s += __shfl_xor(s,2); s += __shfl_xor(s,4);
      if (sg==0) a.outp[(size_t)b4*32000 + nm*400 + (tau-1)] = s + a.bout[nm];
    }
    __syncthreads();
    if (tau<400 && tid<256){
      for(int i=tid;i<1024;i+=256) sA[i] = a.Wloc[(q4*32 + (i>>5))*32 + (i&31)];
    }
    if (tid<32) sv[tid] = a.v_att[q4*32+tid];
    __syncthreads();
    if (tau<400 && tid<256){
      int t = tid;
      float lc[32];
      const float* lb = a.locT + (size_t)b4*8192 + t;
      #pragma unroll
      for(int f=0;f<32;f++) lc[f] = ldf(lb + f*256);
      const float* kb = a.keyp + ((size_t)b4*256 + t)*128 + q4*32;
      float acc=0.f;
      for(int mm=0;mm<32;mm++){
        float lf=0.f;
        #pragma unroll
        for(int f=0;f<32;f++) lf += lc[f]*sA[mm*32+f];
        acc += tanh_(sq[mm] + kb[mm] + lf)*sv[mm];
      }
      stf(a.eP + b4*1024 + t*4 + q4, acc);
    }
    if (tau==400) break;
    gbar(a.bar, bt);
    // ================= Phase C =================
    {
      float e=0.f, pe=0.f, mx=0.f;
      if (tid<256){
        const float* ep = a.eP + b4*1024 + tid*4;
        e = ldf(ep+0)+ldf(ep+1)+ldf(ep+2)+ldf(ep+3);
        if (!mv) e = -1e9f;
        mx = e;
        #pragma unroll
        for(int off=1;off<64;off<<=1) mx = fmaxf(mx, __shfl_xor(mx,off));
        if (lan==0) red[wav] = mx;
      }
      __syncthreads();
      if (tid<256){
        mx = fmaxf(fmaxf(red[0],red[1]), fmaxf(red[2],red[3]));
        pe = __expf(e-mx);
        float sm = pe;
        #pragma unroll
        for(int off=1;off<64;off<<=1) sm += __shfl_xor(sm,off);
        if (lan==0) red[4+wav] = sm;
      }
      __syncthreads();
      if (tid<256){
        float sm = red[4]+red[5]+red[6]+red[7];
        float awt = pe/sm;
        if (q4==0){
          stf(a.aw + b4*256+tid, awt);
          stf(a.awc + b4*256+tid, ldf(a.awc + b4*256+tid) + awt);
          a.wout[(size_t)b4*102400 + (size_t)tid*400 + tau] = awt;
        }
        sA[tid] = awt;
      }
      __syncthreads();
      {
        int fl = tid&127, th = tid>>7;
        const float* xp = a.xin + ((size_t)(b4*256 + th*64))*512 + q4*128 + fl;
        float s=0.f;
        for(int i=0;i<64;i++) s += sA[th*64+i]*xp[(size_t)i*512];
        sA[256+tid] = s;
      }
      __syncthreads();
      if (tid<128){
        float v = sA[256+tid] + sA[384+tid] + sA[512+tid] + sA[640+tid];
        int idx = b4*512 + q4*128 + tid;
        stf(a.ctxf + idx, v);
        sth(a.ctxh + idx, f2b(v));
      }
    }
    gbar(a.bar, bt);
  }
}

extern "C" void kernel_launch(void* const* d_in, const int* in_sizes, int n_in,
                              void* d_out, int out_size, void* d_ws, size_t ws_size,
                              hipStream_t stream){
  (void)in_sizes; (void)n_in; (void)out_size; (void)ws_size;
  const float* xin   = (const float*)d_in[0];
  const float* target= (const float*)d_in[2];
  const float* Wpre1 = (const float*)d_in[3];
  const float* bpre1 = (const float*)d_in[4];
  const float* Wpre2 = (const float*)d_in[5];
  const float* bpre2 = (const float*)d_in[6];
  const float* Wq    = (const float*)d_in[7];
  const float* Wk    = (const float*)d_in[8];
  const float* loc_conv = (const float*)d_in[9];
  const float* Wloc  = (const float*)d_in[10];
  const float* v_att = (const float*)d_in[11];
  const float* Wih1  = (const float*)d_in[12];
  const float* Whh1  = (const float*)d_in[13];
  const float* bih1  = (const float*)d_in[14];
  const float* bhh1  = (const float*)d_in[15];
  const float* Wih2  = (const float*)d_in[16];
  const float* Whh2  = (const float*)d_in[17];
  const float* bih2  = (const float*)d_in[18];
  const float* bhh2  = (const float*)d_in[19];
  const float* Wout  = (const float*)d_in[20];
  const float* boutp = (const float*)d_in[21];

  char* w = (char*)d_ws;
  auto carve=[&](size_t bytes)->void*{ void* r=(void*)w; w += (bytes+255)&~(size_t)255; return r; };
  // state region (zeroed every launch) — must stay first & contiguous
  unsigned short* h1h = (unsigned short*)carve((size_t)2*64*1024*2);
  unsigned short* h2h = (unsigned short*)carve((size_t)2*64*1024*2);
  unsigned short* ctxh= (unsigned short*)carve((size_t)64*512*2);
  float* h1f = (float*)carve((size_t)64*1024*4);
  float* h2f = (float*)carve((size_t)64*1024*4);
  float* ctxf= (float*)carve((size_t)64*512*4);
  float* c1  = (float*)carve((size_t)64*1024*4);
  float* c2  = (float*)carve((size_t)64*1024*4);
  float* aw  = (float*)carve((size_t)64*256*4);
  float* awc = (float*)carve((size_t)64*256*4);
  unsigned* bar = (unsigned*)carve(256);
  int* mflag = (int*)carve(256);
  size_t state_bytes = (size_t)(w - (char*)d_ws);
  float* eP   = (float*)carve((size_t)64*256*4*4);
  float* locT = (float*)carve((size_t)64*32*256*4);
  float* keyp = (float*)carve((size_t)64*256*128*4);
  unsigned short* xbh = (unsigned short*)carve((size_t)400*64*256*2);
  float* bsum1 = (float*)carve((size_t)4096*4);
  float* bsum2 = (float*)carve((size_t)4096*4);
  unsigned short* Wp1h = (unsigned short*)carve((size_t)256*56*512*2);
  unsigned short* Wp2h = (unsigned short*)carve((size_t)256*80*512*2);

  hipMemsetAsync(d_ws, 0, state_bytes, stream);
  maskdet_k<<<1, 256, 0, stream>>>((const unsigned*)d_in[1], mflag);
  prenet_k<<<400, 256, 0, stream>>>(target, Wpre1, bpre1, Wpre2, bpre2, xbh);
  keyproj_k<<<1024, 128, 0, stream>>>(xin, Wk, keyp);
  prep_k<<<16, 256, 0, stream>>>(bih1,bhh1,bih2,bhh2,bsum1,bsum2);
  perm_k<<<2048, 256, 0, stream>>>(Wih1,Whh1,Wih2,Whh2,Wp1h,Wp2h);

  SArgs a;
  a.xin=xin; a.loc_conv=loc_conv; a.Wloc=Wloc; a.v_att=v_att; a.bout=boutp;
  a.Wq=Wq; a.Wout=Wout;
  a.keyp=keyp; a.xbh=xbh;
  a.Wp1h=Wp1h; a.Wp2h=Wp2h;
  a.bsum1=bsum1; a.bsum2=bsum2;
  a.mask8=(const unsigned char*)d_in[1]; a.mask32=(const int*)d_in[1]; a.mflag=mflag;
  a.h1h=h1h; a.h1f=h1f;
  a.h2h=h2h; a.h2f=h2f;
  a.ctxh=ctxh; a.ctxf=ctxf;
  a.c1=c1; a.c2=c2;
  a.aw=aw; a.awc=awc; a.eP=eP; a.locT=locT; a.bar=bar;
  a.outp=(float*)d_out; a.wout=(float*)d_out + (size_t)64*80*400;

  hipFuncSetAttribute((const void*)scan_kernel, hipFuncAttributeMaxDynamicSharedMemorySize, DYNB);
  scan_kernel<<<dim3(NB), dim3(NT), DYNB, stream>>>(a);
}

// Round 17
// 57216.705 us; speedup vs baseline: 5.9116x; 1.1963x over previous
//
#include <hip/hip_runtime.h>

#define NB 256
#define NT 512
#define DYNB 158496
#define SCOPE __HIP_MEMORY_SCOPE_AGENT

typedef __attribute__((ext_vector_type(8))) short short8;
typedef __attribute__((ext_vector_type(4))) float f32x4;

__device__ __forceinline__ float b2f(unsigned short s){ return __uint_as_float(((unsigned)s)<<16); }
__device__ __forceinline__ unsigned short f2b(float f){
  unsigned u = __float_as_uint(f);
  return (unsigned short)((u + 0x7FFFu + ((u>>16)&1u))>>16);
}
__device__ __forceinline__ float sigm(float x){ return 1.0f/(1.0f+__expf(-x)); }
__device__ __forceinline__ float tanh_(float x){ float e=__expf(-2.0f*x); return (1.0f-e)/(1.0f+e); }
__device__ __forceinline__ f32x4 mfma16(short8 a, short8 b, f32x4 c){
  return __builtin_amdgcn_mfma_f32_16x16x32_bf16(a,b,c,0,0,0);
}

// device-coherent access helpers (bypass incoherent L1/L2; no invalidates needed)
__device__ __forceinline__ unsigned long long ldu64(const void* p){
  return __hip_atomic_load((const unsigned long long*)p, __ATOMIC_RELAXED, SCOPE);
}
__device__ __forceinline__ short8 ld8h(const unsigned short* p){
  union{ unsigned long long u[2]; short8 s; } r;
  r.u[0]=ldu64(p); r.u[1]=ldu64(p+4);
  return r.s;
}
__device__ __forceinline__ float2 ld2f(const float* p){
  union{ unsigned long long u; float2 f; } r; r.u=ldu64(p); return r.f;
}
__device__ __forceinline__ float ldf(const float* p){
  return __hip_atomic_load((float*)p, __ATOMIC_RELAXED, SCOPE);
}
__device__ __forceinline__ void stf(float* p, float v){
  __hip_atomic_store(p, v, __ATOMIC_RELAXED, SCOPE);
}
__device__ __forceinline__ void sth(unsigned short* p, unsigned short v){
  __hip_atomic_store(p, v, __ATOMIC_RELAXED, SCOPE);
}

__device__ __forceinline__ void gbar(unsigned* bar, unsigned& target){
  __syncthreads();
  if (threadIdx.x==0){
    target += NB;
    asm volatile("s_waitcnt vmcnt(0)" ::: "memory");
    __hip_atomic_fetch_add(bar, 1u, __ATOMIC_RELAXED, SCOPE);
    while (__hip_atomic_load(bar, __ATOMIC_RELAXED, SCOPE) < target){
      __builtin_amdgcn_s_sleep(1);
    }
  }
  __syncthreads();
}

// ---------------- precompute kernels ----------------

__global__ void maskdet_k(const unsigned* __restrict__ m32, int* __restrict__ flag){
  __shared__ int ok;
  if (threadIdx.x==0) ok = 1;
  __syncthreads();
  for (int i=threadIdx.x; i<4096; i+=256){
    if (m32[i] > 1u) ok = 0;
  }
  __syncthreads();
  if (threadIdx.x==0) *flag = ok;
}

__global__ void xin2bf_k(const float* __restrict__ xin, unsigned short* __restrict__ xinh){
  size_t i = (size_t)blockIdx.x*256 + threadIdx.x;
  if (i < (size_t)64*256*512) xinh[i] = f2b(xin[i]);
}

__global__ void prenet_k(const float* __restrict__ target, const float* __restrict__ W1, const float* __restrict__ b1,
                         const float* __restrict__ W2, const float* __restrict__ b2,
                         unsigned short* __restrict__ xbh){
  int t = blockIdx.x;
  int tid = threadIdx.x;
  __shared__ float stgt[64][80];
  __shared__ float smid[64][256];
  for(int i=tid;i<64*80;i+=256){
    int b=i/80, c=i%80;
    stgt[b][c] = (t==0)?0.f : target[((size_t)b*80+c)*400 + (t-1)];
  }
  __syncthreads();
  {
    float w1r[80];
    #pragma unroll
    for(int c=0;c<80;c++) w1r[c] = W1[tid*80+c];
    float bb1 = b1[tid];
    for(int b0=0;b0<64;b0+=16){
      float acc[16];
      #pragma unroll
      for(int i=0;i<16;i++) acc[i]=0.f;
      for(int c=0;c<80;c++){
        float wv=w1r[c];
        #pragma unroll
        for(int i=0;i<16;i++) acc[i] += wv*stgt[b0+i][c];
      }
      #pragma unroll
      for(int i=0;i<16;i++) smid[b0+i][tid] = fmaxf(acc[i]+bb1, 0.f);
    }
  }
  __syncthreads();
  {
    float bb2 = b2[tid];
    for(int b0=0;b0<64;b0+=16){
      float acc[16];
      #pragma unroll
      for(int i=0;i<16;i++) acc[i]=0.f;
      for(int c=0;c<256;c++){
        float wv=W2[tid*256+c];
        #pragma unroll
        for(int i=0;i<16;i++) acc[i] += wv*smid[b0+i][c];
      }
      #pragma unroll
      for(int i=0;i<16;i++){
        float v = fmaxf(acc[i]+bb2,0.f);
        xbh[((size_t)t*64 + b0+i)*256 + tid] = f2b(v);
      }
    }
  }
}

// writes keypT[b][m][t] as bf16 (transposed + halved)
__global__ void keyproj_k(const float* __restrict__ xin, const float* __restrict__ Wk, unsigned short* __restrict__ keypT){
  int b = blockIdx.x>>4; int t0=(blockIdx.x&15)*16; int m=threadIdx.x; // 128 threads
  __shared__ float sx[16][512];
  for(int i=m;i<16*512;i+=128){ int tt=i>>9, f=i&511; sx[tt][f]=xin[((size_t)b*256+t0+tt)*512+f]; }
  __syncthreads();
  float s[16];
  #pragma unroll
  for(int i=0;i<16;i++) s[i]=0.f;
  for(int f=0;f<512;f++){
    float wv = Wk[m*512+f];
    #pragma unroll
    for(int i=0;i<16;i++) s[i]+=sx[i][f]*wv;
  }
  #pragma unroll
  for(int i=0;i<16;i++) keypT[((size_t)b*128+m)*256 + t0+i] = f2b(s[i]);
}

__global__ void prep_k(const float* bih1,const float* bhh1,const float* bih2,const float* bhh2,
                       float* bsum1,float* bsum2){
  int i0 = blockIdx.x*blockDim.x + threadIdx.x;
  int n = gridDim.x*blockDim.x;
  for(int k=i0;k<4096;k+=n){ bsum1[k]=bih1[k]+bhh1[k]; bsum2[k]=bih2[k]+bhh2[k]; }
}

__global__ void perm_k(const float* __restrict__ Wih1, const float* __restrict__ Whh1,
                       const float* __restrict__ Wih2, const float* __restrict__ Whh2,
                       unsigned short* __restrict__ Wp1h, unsigned short* __restrict__ Wp2h){
  size_t i0 = (size_t)blockIdx.x*blockDim.x + threadIdx.x;
  size_t n  = (size_t)gridDim.x*blockDim.x;
  const size_t N1 = (size_t)256*56*512;
  for(size_t idx=i0; idx<N1; idx+=n){
    int beta = (int)(idx/28672);
    int r = (int)(idx%28672);
    int kt = r/512;
    int l  = (r>>3)&63;
    int i8 = r&7;
    int c = l&15, cci = l>>4;
    int k = kt*32 + cci*8 + i8;
    int rowp = (c>>2)*1024 + beta*4 + (c&3);
    float v = (k<768)? Wih1[(size_t)rowp*768 + k] : Whh1[(size_t)rowp*1024 + (k-768)];
    Wp1h[idx] = f2b(v);
  }
  const size_t N2 = (size_t)256*80*512;
  for(size_t idx=i0; idx<N2; idx+=n){
    int beta = (int)(idx/40960);
    int r = (int)(idx%40960);
    int kt = r/512;
    int l  = (r>>3)&63;
    int i8 = r&7;
    int c = l&15, cci = l>>4;
    int k = kt*32 + cci*8 + i8;
    int rowp = (c>>2)*1024 + beta*4 + (c&3);
    float v = (k<1536)? Wih2[(size_t)rowp*1536 + k] : Whh2[(size_t)rowp*1024 + (k-1536)];
    Wp2h[idx] = f2b(v);
  }
}

// ---------------- the scan ----------------

struct SArgs {
  const float* xin; const float* loc_conv; const float* Wloc; const float* v_att; const float* bout;
  const float* Wq; const float* Wout;
  const unsigned short* keypT; const unsigned short* xinh;
  const unsigned short* xbh;
  const unsigned short* Wp1h; const unsigned short* Wp2h;
  const float* bsum1; const float* bsum2;
  const unsigned char* mask8; const int* mask32; const int* mflag;
  unsigned short* h1h; float* h1f;
  unsigned short* h2h; float* h2f;
  unsigned short* ctxh; float* ctxf;
  float* c1; float* c2;
  float* aw; float* awc; float* eP; float* locT;
  unsigned* bar;
  float* outp; float* wout;
};

__global__ void __launch_bounds__(NT) scan_kernel(SArgs a){
  extern __shared__ char dynsm[];
  unsigned short* Lw1 = (unsigned short*)dynsm;             // 28672
  unsigned short* Lw2 = (unsigned short*)(dynsm + 57344);   // 40960
  float* gsc1 = (float*)(dynsm + 139264);                   // [64][17]
  float* gsc2 = (float*)(dynsm + 143616);                   // [64][17]
  float* sA   = (float*)(dynsm + 147968);                   // [2560]
  float* sq   = (float*)(dynsm + 158208);                   // [32]
  float* sv   = (float*)(dynsm + 158336);                   // [32]
  float* red  = (float*)(dynsm + 158464);                   // [8]

  const int beta = blockIdx.x;
  const int tid = threadIdx.x;
  const int wav = tid>>6;
  const int lan = tid&63;

  const int cc  = lan>>4;
  const int b4  = beta>>2;
  const int q4  = beta&3;
  unsigned bt = 0;

  {
    const short8* g1 = (const short8*)(a.Wp1h + (size_t)beta*28672);
    short8* l1 = (short8*)Lw1;
    for (int i=tid; i<3584; i+=NT) l1[i] = g1[i];
    const short8* g2 = (const short8*)(a.Wp2h + (size_t)beta*40960);
    short8* l2 = (short8*)Lw2;
    for (int i=tid; i<5120; i+=NT) l2[i] = g2[i];
  }

  bool mv = false;
  if (tid<256) mv = (a.mflag[0] ? (a.mask32[b4*256+tid] != 0) : (a.mask8[b4*256+tid] != 0));
  __syncthreads();

  for (int tau=0; tau<=400; ++tau){
    const int p = tau&1;
    // ================= Phase A: LSTM1 (waves 0-3) ∥ LSTM2 (waves 4-7) =================
    if (tau<400 && wav<4){
      const int row = wav*16 + (lan&15);
      f32x4 A0={0.f,0.f,0.f,0.f};
      const unsigned short* wh = Lw1 + lan*8;
      {
        const unsigned short* xh = a.xbh + ((size_t)tau*64 + row)*256 + cc*8;
        #pragma unroll
        for(int kt=0;kt<8;kt++)
          A0=mfma16(*(const short8*)(xh+kt*32), *(const short8*)(wh+kt*512), A0);
      }
      {
        const unsigned short* xh = a.ctxh + row*512 + cc*8;
        #pragma unroll 8
        for(int kt=8;kt<24;kt++)
          A0=mfma16(ld8h(xh+(kt-8)*32), *(const short8*)(wh+kt*512), A0);
      }
      {
        const unsigned short* xh = a.h1h + (size_t)(p^1)*65536 + row*1024 + cc*8;
        #pragma unroll 8
        for(int kt=24;kt<56;kt++)
          A0=mfma16(ld8h(xh+(kt-24)*32), *(const short8*)(wh+kt*512), A0);
      }
      #pragma unroll
      for(int r=0;r<4;r++) gsc1[(wav*16 + cc*4 + r)*17 + (lan&15)] = A0[r];
    }
    if (tau>0 && wav>=4){
      const int wv2 = wav-4;
      const int row = wv2*16 + (lan&15);
      f32x4 A0={0.f,0.f,0.f,0.f};
      const unsigned short* wh = Lw2 + lan*8;
      {
        const unsigned short* xh = a.h1h + (size_t)(p^1)*65536 + row*1024 + cc*8;
        #pragma unroll 8
        for(int kt=0;kt<32;kt++)
          A0=mfma16(ld8h(xh+kt*32), *(const short8*)(wh+kt*512), A0);
      }
      {
        const unsigned short* xh = a.ctxh + row*512 + cc*8;
        #pragma unroll 8
        for(int kt=32;kt<48;kt++)
          A0=mfma16(ld8h(xh+(kt-32)*32), *(const short8*)(wh+kt*512), A0);
      }
      {
        const unsigned short* xh = a.h2h + (size_t)p*65536 + row*1024 + cc*8;
        #pragma unroll 8
        for(int kt=48;kt<80;kt++)
          A0=mfma16(ld8h(xh+(kt-48)*32), *(const short8*)(wh+kt*512), A0);
      }
      #pragma unroll
      for(int r=0;r<4;r++) gsc2[(wv2*16 + cc*4 + r)*17 + (lan&15)] = A0[r];
    }
    __syncthreads();
    if (tau<400 && tid<256){
      int m = tid>>2, j = tid&3, u = beta*4+j;
      float gi = gsc1[m*17+0+j]  + a.bsum1[0*1024+u];
      float gf = gsc1[m*17+4+j]  + a.bsum1[1*1024+u];
      float gg = gsc1[m*17+8+j]  + a.bsum1[2*1024+u];
      float go = gsc1[m*17+12+j] + a.bsum1[3*1024+u];
      float cp = a.c1[m*1024+u];
      float cn = sigm(gf)*cp + sigm(gi)*tanh_(gg);
      a.c1[m*1024+u] = cn;
      float hn = sigm(go)*tanh_(cn);
      stf(a.h1f + m*1024+u, hn);
      sth(a.h1h + (size_t)p*65536 + m*1024 + u, f2b(hn));
    }
    if (tau>0 && tid>=256){
      int t2 = tid-256;
      int m = t2>>2, j = t2&3, u = beta*4+j;
      float gi = gsc2[m*17+0+j]  + a.bsum2[0*1024+u];
      float gf = gsc2[m*17+4+j]  + a.bsum2[1*1024+u];
      float gg = gsc2[m*17+8+j]  + a.bsum2[2*1024+u];
      float go = gsc2[m*17+12+j] + a.bsum2[3*1024+u];
      float cp = a.c2[m*1024+u];
      float cn = sigm(gf)*cp + sigm(gi)*tanh_(gg);
      a.c2[m*1024+u] = cn;
      float hn = sigm(go)*tanh_(cn);
      stf(a.h2f + m*1024+u, hn);
      sth(a.h2h + (size_t)(p^1)*65536 + m*1024 + u, f2b(hn));
    }
    if (tau<400){
      if (tid<128){
        float2 v = ld2f(a.aw + b4*256 + tid*2);
        sA[tid*2]=v.x; sA[tid*2+1]=v.y;
        float2 w2 = ld2f(a.awc + b4*256 + tid*2);
        sA[256+tid*2]=w2.x; sA[257+tid*2]=w2.y;
      }
      for(int i=tid;i<1984;i+=NT) sA[512+i] = a.loc_conv[i];
    }
    __syncthreads();
    if (tau<400){
      const int t0 = q4*64;
      #pragma unroll
      for(int jj=0;jj<4;jj++){
        int o = tid*4+jj;
        int f = o>>6, tl = o&63, t = t0+tl;
        float s = 0.f;
        #pragma unroll
        for(int c=0;c<2;c++){
          const float* kw = &sA[512 + (f*2+c)*31];
          const float* wv = &sA[c*256];
          for(int k=0;k<31;k++){
            int tt = t + k - 15;
            if (tt>=0 && tt<256) s += wv[tt]*kw[k];
          }
        }
        stf(a.locT + (size_t)b4*8192 + f*256 + t, s);
      }
    }
    gbar(a.bar, bt);
    // ================= Phase B: q/e path (tid<256) ∥ out-proj (tid 256-415) =================
    if (tau<400 && tid<256){
      for(int i=tid*2;i<1024;i+=512){
        float2 v = ld2f(a.h1f + b4*1024 + i);
        sA[i]=v.x; sA[i+1]=v.y;
      }
    }
    if (tau>0 && tid>=256){
      int t2 = tid-256;
      for(int i=t2*2;i<1024;i+=512){
        float2 v = ld2f(a.h2f + b4*1024 + i);
        sA[1024+i]=v.x; sA[1025+i]=v.y;
      }
      {
        float2 v = ld2f(a.ctxf + b4*512 + t2*2);
        sA[2048+t2*2]=v.x; sA[2049+t2*2]=v.y;
      }
    }
    __syncthreads();
    if (tau<400 && tid<256){
      int ml = tid>>3, sg = tid&7;
      const float* wq = a.Wq + (size_t)(q4*32+ml)*1024;
      float s=0.f;
      #pragma unroll 8
      for(int i=0;i<128;i++) s += sA[sg + i*8]*wq[sg + i*8];
      s += __shfl_xor(s,1); s += __shfl_xor(s,2); s += __shfl_xor(s,4);
      if (sg==0) sq[ml] = s;
    }
    if (tau>0 && tid>=256 && tid<416){
      int t2 = tid-256;
      int nl = t2>>3, sg = t2&7, nm = q4*20+nl;
      const float* wo = a.Wout + (size_t)nm*1536;
      float s=0.f;
      #pragma unroll 8
      for(int i=0;i<192;i++) s += sA[1024 + sg + i*8]*wo[sg + i*8];
      s += __shfl_xor(s,1); s += __shfl_xor(s,2); s += __shfl_xor(s,4);
      if (sg==0) a.outp[(size_t)b4*32000 + nm*400 + (tau-1)] = s + a.bout[nm];
    }
    __syncthreads();
    if (tau<400 && tid<256){
      for(int i=tid;i<1024;i+=256) sA[i] = a.Wloc[(q4*32 + (i>>5))*32 + (i&31)];
    }
    if (tid<32) sv[tid] = a.v_att[q4*32+tid];
    __syncthreads();
    if (tau<400 && tid<256){
      int t = tid;
      float lc[32];
      const float* lb = a.locT + (size_t)b4*8192 + t;
      #pragma unroll
      for(int f=0;f<32;f++) lc[f] = ldf(lb + f*256);
      const unsigned short* kb = a.keypT + ((size_t)b4*128 + q4*32)*256 + t;
      float acc=0.f;
      for(int mm=0;mm<32;mm++){
        float lf=0.f;
        #pragma unroll
        for(int f=0;f<32;f++) lf += lc[f]*sA[mm*32+f];
        acc += tanh_(sq[mm] + b2f(kb[mm*256]) + lf)*sv[mm];
      }
      stf(a.eP + b4*1024 + t*4 + q4, acc);
    }
    if (tau==400) break;
    gbar(a.bar, bt);
    // ================= Phase C =================
    {
      float e=0.f, pe=0.f, mx=0.f;
      if (tid<256){
        const float* ep = a.eP + b4*1024 + tid*4;
        e = ldf(ep+0)+ldf(ep+1)+ldf(ep+2)+ldf(ep+3);
        if (!mv) e = -1e9f;
        mx = e;
        #pragma unroll
        for(int off=1;off<64;off<<=1) mx = fmaxf(mx, __shfl_xor(mx,off));
        if (lan==0) red[wav] = mx;
      }
      __syncthreads();
      if (tid<256){
        mx = fmaxf(fmaxf(red[0],red[1]), fmaxf(red[2],red[3]));
        pe = __expf(e-mx);
        float sm = pe;
        #pragma unroll
        for(int off=1;off<64;off<<=1) sm += __shfl_xor(sm,off);
        if (lan==0) red[4+wav] = sm;
      }
      __syncthreads();
      if (tid<256){
        float sm = red[4]+red[5]+red[6]+red[7];
        float awt = pe/sm;
        if (q4==0){
          stf(a.aw + b4*256+tid, awt);
          stf(a.awc + b4*256+tid, ldf(a.awc + b4*256+tid) + awt);
          a.wout[(size_t)b4*102400 + (size_t)tid*400 + tau] = awt;
        }
        sA[tid] = awt;
      }
      __syncthreads();
      {
        int fl = tid&127, th = tid>>7;
        const unsigned short* xp = a.xinh + ((size_t)(b4*256 + th*64))*512 + q4*128 + fl;
        float s=0.f;
        for(int i=0;i<64;i++) s += sA[th*64+i]*b2f(xp[(size_t)i*512]);
        sA[256+tid] = s;
      }
      __syncthreads();
      if (tid<128){
        float v = sA[256+tid] + sA[384+tid] + sA[512+tid] + sA[640+tid];
        int idx = b4*512 + q4*128 + tid;
        stf(a.ctxf + idx, v);
        sth(a.ctxh + idx, f2b(v));
      }
    }
    gbar(a.bar, bt);
  }
}

extern "C" void kernel_launch(void* const* d_in, const int* in_sizes, int n_in,
                              void* d_out, int out_size, void* d_ws, size_t ws_size,
                              hipStream_t stream){
  (void)in_sizes; (void)n_in; (void)out_size; (void)ws_size;
  const float* xin   = (const float*)d_in[0];
  const float* target= (const float*)d_in[2];
  const float* Wpre1 = (const float*)d_in[3];
  const float* bpre1 = (const float*)d_in[4];
  const float* Wpre2 = (const float*)d_in[5];
  const float* bpre2 = (const float*)d_in[6];
  const float* Wq    = (const float*)d_in[7];
  const float* Wk    = (const float*)d_in[8];
  const float* loc_conv = (const float*)d_in[9];
  const float* Wloc  = (const float*)d_in[10];
  const float* v_att = (const float*)d_in[11];
  const float* Wih1  = (const float*)d_in[12];
  const float* Whh1  = (const float*)d_in[13];
  const float* bih1  = (const float*)d_in[14];
  const float* bhh1  = (const float*)d_in[15];
  const float* Wih2  = (const float*)d_in[16];
  const float* Whh2  = (const float*)d_in[17];
  const float* bih2  = (const float*)d_in[18];
  const float* bhh2  = (const float*)d_in[19];
  const float* Wout  = (const float*)d_in[20];
  const float* boutp = (const float*)d_in[21];

  char* w = (char*)d_ws;
  auto carve=[&](size_t bytes)->void*{ void* r=(void*)w; w += (bytes+255)&~(size_t)255; return r; };
  // state region (zeroed every launch) — must stay first & contiguous
  unsigned short* h1h = (unsigned short*)carve((size_t)2*64*1024*2);
  unsigned short* h2h = (unsigned short*)carve((size_t)2*64*1024*2);
  unsigned short* ctxh= (unsigned short*)carve((size_t)64*512*2);
  float* h1f = (float*)carve((size_t)64*1024*4);
  float* h2f = (float*)carve((size_t)64*1024*4);
  float* ctxf= (float*)carve((size_t)64*512*4);
  float* c1  = (float*)carve((size_t)64*1024*4);
  float* c2  = (float*)carve((size_t)64*1024*4);
  float* aw  = (float*)carve((size_t)64*256*4);
  float* awc = (float*)carve((size_t)64*256*4);
  unsigned* bar = (unsigned*)carve(256);
  int* mflag = (int*)carve(256);
  size_t state_bytes = (size_t)(w - (char*)d_ws);
  float* eP   = (float*)carve((size_t)64*256*4*4);
  float* locT = (float*)carve((size_t)64*32*256*4);
  unsigned short* keypT = (unsigned short*)carve((size_t)64*128*256*2);
  unsigned short* xinh  = (unsigned short*)carve((size_t)64*256*512*2);
  unsigned short* xbh = (unsigned short*)carve((size_t)400*64*256*2);
  float* bsum1 = (float*)carve((size_t)4096*4);
  float* bsum2 = (float*)carve((size_t)4096*4);
  unsigned short* Wp1h = (unsigned short*)carve((size_t)256*56*512*2);
  unsigned short* Wp2h = (unsigned short*)carve((size_t)256*80*512*2);

  hipMemsetAsync(d_ws, 0, state_bytes, stream);
  maskdet_k<<<1, 256, 0, stream>>>((const unsigned*)d_in[1], mflag);
  xin2bf_k<<<32768, 256, 0, stream>>>(xin, xinh);
  prenet_k<<<400, 256, 0, stream>>>(target, Wpre1, bpre1, Wpre2, bpre2, xbh);
  keyproj_k<<<1024, 128, 0, stream>>>(xin, Wk, keypT);
  prep_k<<<16, 256, 0, stream>>>(bih1,bhh1,bih2,bhh2,bsum1,bsum2);
  perm_k<<<2048, 256, 0, stream>>>(Wih1,Whh1,Wih2,Whh2,Wp1h,Wp2h);

  SArgs a;
  a.xin=xin; a.loc_conv=loc_conv; a.Wloc=Wloc; a.v_att=v_att; a.bout=boutp;
  a.Wq=Wq; a.Wout=Wout;
  a.keypT=keypT; a.xinh=xinh; a.xbh=xbh;
  a.Wp1h=Wp1h; a.Wp2h=Wp2h;
  a.bsum1=bsum1; a.bsum2=bsum2;
  a.mask8=(const unsigned char*)d_in[1]; a.mask32=(const int*)d_in[1]; a.mflag=mflag;
  a.h1h=h1h; a.h1f=h1f;
  a.h2h=h2h; a.h2f=h2f;
  a.ctxh=ctxh; a.ctxf=ctxf;
  a.c1=c1; a.c2=c2;
  a.aw=aw; a.awc=awc; a.eP=eP; a.locT=locT; a.bar=bar;
  a.outp=(float*)d_out; a.wout=(float*)d_out + (size_t)64*80*400;

  hipFuncSetAttribute((const void*)scan_kernel, hipFuncAttributeMaxDynamicSharedMemorySize, DYNB);
  scan_kernel<<<dim3(NB), dim3(NT), DYNB, stream>>>(a);
}